// Round 14
// baseline (265.496 us; speedup 1.0000x reference)
//
#include <hip/hip_runtime.h>

#define EMBED 1024
#define THREE_EMBED 3072
#define HEADS 16
#define HDIM 64
#define SEQ 2048
#define BATCH 2
#define MTOT 4096  // B*T

typedef short bf16x8 __attribute__((ext_vector_type(8)));
typedef float f32x4 __attribute__((ext_vector_type(4)));

#define MFMA16(a, b, c) __builtin_amdgcn_mfma_f32_16x16x32_bf16(a, b, c, 0, 0, 0)

__device__ __forceinline__ unsigned short f2bf(float f) {
  union { float f; unsigned int u; } v; v.f = f;
  unsigned int r = v.u + 0x7fffu + ((v.u >> 16) & 1u);
  return (unsigned short)(r >> 16);
}

// async 16B global->LDS. LDS dest is wave-uniform base + lane*16 (HW semantics).
__device__ __forceinline__ void gload_lds16(const unsigned short* g, unsigned short* l) {
  __builtin_amdgcn_global_load_lds(
      (const __attribute__((address_space(1))) void*)g,
      (__attribute__((address_space(3))) void*)l, 16, 0, 0);
}

__device__ __forceinline__ void wait_vm0_barrier() {
  asm volatile("s_waitcnt vmcnt(0)" ::: "memory");
  __builtin_amdgcn_s_barrier();
}

template <int N>
__device__ __forceinline__ void wait_vmcnt() {
  if constexpr (N == 0) asm volatile("s_waitcnt vmcnt(0)" ::: "memory");
  else if constexpr (N == 1) asm volatile("s_waitcnt vmcnt(1)" ::: "memory");
  else if constexpr (N == 2) asm volatile("s_waitcnt vmcnt(2)" ::: "memory");
  else if constexpr (N == 3) asm volatile("s_waitcnt vmcnt(3)" ::: "memory");
  else if constexpr (N == 4) asm volatile("s_waitcnt vmcnt(4)" ::: "memory");
  else if constexpr (N == 6) asm volatile("s_waitcnt vmcnt(6)" ::: "memory");
  else if constexpr (N == 8) asm volatile("s_waitcnt vmcnt(8)" ::: "memory");
}

__device__ __forceinline__ void open_phase_barrier() {
  __builtin_amdgcn_s_barrier();
  __builtin_amdgcn_sched_barrier(0);  // keep ds_reads below the barrier (rule #18)
}

// ---------------- transpose fp32 [K][N] -> bf16 [N][K] ----------------
__global__ __launch_bounds__(256) void k_transpose_bf16(
    const float* __restrict__ in, unsigned short* __restrict__ out, int K, int N) {
  __shared__ float t[32][33];
  int tx = threadIdx.x & 31, ty = threadIdx.x >> 5;
  int n0 = blockIdx.x * 32, k0 = blockIdx.y * 32;
#pragma unroll
  for (int i = 0; i < 32; i += 8)
    t[ty + i][tx] = in[(size_t)(k0 + ty + i) * N + n0 + tx];
  __syncthreads();
#pragma unroll
  for (int i = 0; i < 32; i += 8)
    out[(size_t)(n0 + ty + i) * K + k0 + tx] = f2bf(t[tx][ty + i]);
}

// ---------------- V transpose: qkv V-part -> Vt[bh][64][2048] bf16 ----------------
__global__ __launch_bounds__(256) void k_transpose_v(
    const unsigned short* __restrict__ qkv, unsigned short* __restrict__ Vt) {
  __shared__ unsigned short t[32][33];
  int tx = threadIdx.x & 31, ty = threadIdx.x >> 5;  // 32 x 8
  int t0 = blockIdx.x * 32;
  int d0 = (blockIdx.y & 1) * 32;
  int bh = blockIdx.y >> 1;
  int b = bh >> 4, h = bh & 15;
  const unsigned short* src = qkv + (size_t)b * SEQ * THREE_EMBED + 2 * EMBED + h * HDIM;
#pragma unroll
  for (int i = 0; i < 32; i += 8)
    t[ty + i][tx] = src[(size_t)(t0 + ty + i) * THREE_EMBED + d0 + tx];
  __syncthreads();
  unsigned short* dst = Vt + (size_t)bh * HDIM * SEQ;
#pragma unroll
  for (int i = 0; i < 32; i += 8)
    dst[(size_t)(d0 + ty + i) * SEQ + t0 + tx] = t[tx][ty + i];
}

// ---------------- layernorm fp32 [4096][1024] -> bf16 ----------------
__global__ __launch_bounds__(256) void k_layernorm(
    const float* __restrict__ x, const float* __restrict__ g,
    const float* __restrict__ b, unsigned short* __restrict__ out) {
  int row = blockIdx.x;
  int tid = threadIdx.x;
  const float4 xv = *(const float4*)(x + (size_t)row * EMBED + tid * 4);
  float s = xv.x + xv.y + xv.z + xv.w;
  float sq = xv.x * xv.x + xv.y * xv.y + xv.z * xv.z + xv.w * xv.w;
#pragma unroll
  for (int off = 1; off < 64; off <<= 1) {
    s += __shfl_xor(s, off);
    sq += __shfl_xor(sq, off);
  }
  __shared__ float red[8];
  int w = tid >> 6;
  if ((tid & 63) == 0) { red[w] = s; red[4 + w] = sq; }
  __syncthreads();
  s = red[0] + red[1] + red[2] + red[3];
  sq = red[4] + red[5] + red[6] + red[7];
  float mu = s * (1.0f / EMBED);
  float var = sq * (1.0f / EMBED) - mu * mu;
  float rs = rsqrtf(var + 1e-5f);
  float xs[4] = {xv.x, xv.y, xv.z, xv.w};
  unsigned short o[4];
#pragma unroll
  for (int c = 0; c < 4; c++) {
    int col = tid * 4 + c;
    o[c] = f2bf((xs[c] - mu) * rs * g[col] + b[col]);
  }
  *(ushort4*)(out + (size_t)row * EMBED + tid * 4) = *(const ushort4*)o;
}

// ======== 256x256 8-wave 4-phase GEMM v2 (register-held operands) ========
// 24 b128 LDS reads per K-tile(64) per wave, uniform vmcnt(4),
// one barrier per phase + sched_barrier(0), tail peeled vmcnt 2->0.
template <int EPI>
__global__ __launch_bounds__(512, 2) void k_gemm8(
    const unsigned short* __restrict__ A, const unsigned short* __restrict__ Bt,
    const float* __restrict__ bias, const float* __restrict__ resid,
    float* __restrict__ outf, unsigned short* __restrict__ outb,
    int M, int N, int K) {
  __shared__ unsigned short lA[2][16384];
  __shared__ unsigned short lB[2][16384];
  int tid = threadIdx.x;
  int nwg = gridDim.x * gridDim.y;
  int bid = blockIdx.y * gridDim.x + blockIdx.x;
  int swz = (bid & 7) * (nwg >> 3) + (bid >> 3);
  int m0 = (swz / gridDim.x) * 256, n0 = (swz % gridDim.x) * 256;
  int lane = tid & 63, w = tid >> 6;
  int lr = lane & 15, lg = lane >> 4;
  int warow = (w >> 2) * 64;  // A row base within a half
  int wbrow = (w & 3) * 32;   // B row base within a half
  int rx = lr & 7;
  int colk[2] = {(lg ^ rx) * 8, ((4 + lg) ^ rx) * 8};
  f32x4 acc[8][4] = {};
  int swzk = ((lane & 7) ^ ((lane >> 3) & 7)) * 8;  // pre-swizzled global col (shorts)
  const unsigned short* gA[2];
  const unsigned short* gB[2];
#pragma unroll
  for (int i = 0; i < 2; i++) {
    int chrow = (w * 2 + i) * 8 + (lane >> 3);
    gA[i] = A + (size_t)(m0 + chrow) * K + swzk;
    gB[i] = Bt + (size_t)(n0 + chrow) * K + swzk;
  }
  int NT = K >> 6;
  auto stageA = [&](int h, int kt, int buf) {
    size_t goff = (size_t)(h * 128) * K + (size_t)kt * 64;
    int lo = h * 8192 + w * 1024;
    gload_lds16(gA[0] + goff, &lA[buf][lo]);
    gload_lds16(gA[1] + goff, &lA[buf][lo + 512]);
  };
  auto stageB = [&](int h, int kt, int buf) {
    size_t goff = (size_t)(h * 128) * K + (size_t)kt * 64;
    int lo = h * 8192 + w * 1024;
    gload_lds16(gB[0] + goff, &lB[buf][lo]);
    gload_lds16(gB[1] + goff, &lB[buf][lo + 512]);
  };
  bf16x8 aX[4][2], aY[4][2], b0[2][2], b1[2][2];
  auto rdA = [&](int buf, int mh, bf16x8 (&dst)[4][2]) {
#pragma unroll
    for (int ii = 0; ii < 4; ii++) {
      int ra = mh * 128 + warow + ii * 16 + lr;
#pragma unroll
      for (int ks = 0; ks < 2; ks++)
        dst[ii][ks] = *(const bf16x8*)&lA[buf][ra * 64 + colk[ks]];
    }
  };
  auto rdB = [&](int buf, int nh, bf16x8 (&dst)[2][2]) {
#pragma unroll
    for (int jj = 0; jj < 2; jj++) {
      int rb = nh * 128 + wbrow + jj * 16 + lr;
#pragma unroll
      for (int ks = 0; ks < 2; ks++)
        dst[jj][ks] = *(const bf16x8*)&lB[buf][rb * 64 + colk[ks]];
    }
  };
  auto mf = [&](int mh, int nh, bf16x8 (&aa)[4][2], bf16x8 (&bb)[2][2]) {
    __builtin_amdgcn_s_setprio(1);
#pragma unroll
    for (int ii = 0; ii < 4; ii++)
#pragma unroll
      for (int jj = 0; jj < 2; jj++)
#pragma unroll
        for (int ks = 0; ks < 2; ks++)
          acc[mh * 4 + ii][nh * 2 + jj] =
              MFMA16(aa[ii][ks], bb[jj][ks], acc[mh * 4 + ii][nh * 2 + jj]);
    __builtin_amdgcn_s_setprio(0);
  };
  stageA(0, 0, 0); stageB(0, 0, 0); stageB(1, 0, 0); stageA(1, 0, 0);
  wait_vmcnt<6>();
  open_phase_barrier();
  rdA(0, 0, aX);
  for (int t = 0; t < NT - 1; t++) {
    int cur = t & 1, nxt = cur ^ 1;
    stageA(0, t + 1, nxt);
    wait_vmcnt<4>();
    open_phase_barrier();
    rdB(cur, 0, b0);
    rdB(cur, 1, b1);
    mf(0, 0, aX, b0);
    stageB(0, t + 1, nxt);
    wait_vmcnt<4>();
    open_phase_barrier();
    rdA(cur, 1, aY);
    mf(0, 1, aX, b1);
    stageB(1, t + 1, nxt);
    wait_vmcnt<4>();
    open_phase_barrier();
    mf(1, 1, aY, b1);
    stageA(1, t + 1, nxt);
    wait_vmcnt<4>();
    open_phase_barrier();
    rdA(nxt, 0, aX);
    mf(1, 0, aY, b0);
  }
  {  // tail tile NT-1 (no staging), tightening drains
    int cur = (NT - 1) & 1;
    wait_vmcnt<2>();
    open_phase_barrier();
    rdB(cur, 0, b0);
    rdB(cur, 1, b1);
    mf(0, 0, aX, b0);
    wait_vmcnt<0>();
    open_phase_barrier();
    rdA(cur, 1, aY);
    mf(0, 1, aX, b1);
    mf(1, 1, aY, b1);
    mf(1, 0, aY, b0);
  }
#pragma unroll
  for (int i = 0; i < 8; i++) {
#pragma unroll
    for (int j = 0; j < 4; j++) {
      int col = n0 + (j >> 1) * 128 + wbrow + (j & 1) * 16 + lr;
      float bv = bias[col];
#pragma unroll
      for (int r = 0; r < 4; r++) {
        int row = m0 + (i >> 2) * 128 + warow + (i & 3) * 16 + lg * 4 + r;
        float v = acc[i][j][r] + bv;
        size_t idx = (size_t)row * N + col;
        if constexpr (EPI == 0) {
          outb[idx] = f2bf(v);
        } else if constexpr (EPI == 1) {
          outf[idx] = v + resid[idx];
        } else {
          float gv = 0.5f * v * (1.0f + erff(v * 0.70710678118654752f));
          outb[idx] = f2bf(gv);
        }
      }
    }
  }
}

// ---- narrow GEMM (BM=128, BN=64, BK=64): 3-buffer counted-vmcnt pipeline ----
template <int EPI>
__global__ __launch_bounds__(256) void k_gemmN(
    const unsigned short* __restrict__ A, const unsigned short* __restrict__ Bt,
    const float* __restrict__ bias, const float* __restrict__ resid,
    float* __restrict__ outf, unsigned short* __restrict__ outb,
    int M, int N, int K) {
  __shared__ unsigned short lA[3][128 * 64];
  __shared__ unsigned short lB[3][64 * 64];
  int tid = threadIdx.x;
  int nwg = gridDim.x * gridDim.y;
  int bid = blockIdx.y * gridDim.x + blockIdx.x;
  int swz = (bid & 7) * (nwg >> 3) + (bid >> 3);
  int m0 = (swz / gridDim.x) * 128, n0 = (swz % gridDim.x) * 64;
  int lane = tid & 63, w = tid >> 6;
  int wm = w * 32;
  int lr = lane & 15, lg = lane >> 4;
  int rx = lr & 7;
  int colk[2] = {(lg ^ rx) * 8, ((4 + lg) ^ rx) * 8};
  f32x4 acc[2][4] = {};
  int swzk = ((lane & 7) ^ ((lane >> 3) & 7)) * 8;  // pre-swizzled global col (shorts)
  const unsigned short* gsrc[6];
  int loff[6];
  bool isa[6];
#pragma unroll
  for (int c0 = 0; c0 < 6; c0++) {
    int c = w * 6 + c0;
    if (c < 16) {
      int row = c * 8 + (lane >> 3);
      gsrc[c0] = A + (size_t)(m0 + row) * K + swzk;
      loff[c0] = c * 512;
      isa[c0] = true;
    } else {
      int row = (c - 16) * 8 + (lane >> 3);
      gsrc[c0] = Bt + (size_t)(n0 + row) * K + swzk;
      loff[c0] = (c - 16) * 512;
      isa[c0] = false;
    }
  }
  auto stage = [&](int k0, int buf) {
#pragma unroll
    for (int c0 = 0; c0 < 6; c0++)
      gload_lds16(gsrc[c0] + k0, isa[c0] ? &lA[buf][loff[c0]] : &lB[buf][loff[c0]]);
  };
  auto compute = [&](int buf) {
    bf16x8 af[2][2], bf[4][2];
#pragma unroll
    for (int i = 0; i < 2; i++)
#pragma unroll
      for (int ks = 0; ks < 2; ks++)
        af[i][ks] = *(const bf16x8*)&lA[buf][(wm + i * 16 + lr) * 64 + colk[ks]];
#pragma unroll
    for (int j = 0; j < 4; j++)
#pragma unroll
      for (int ks = 0; ks < 2; ks++)
        bf[j][ks] = *(const bf16x8*)&lB[buf][(j * 16 + lr) * 64 + colk[ks]];
    __builtin_amdgcn_s_setprio(1);
#pragma unroll
    for (int i = 0; i < 2; i++)
#pragma unroll
      for (int j = 0; j < 4; j++)
#pragma unroll
        for (int ks = 0; ks < 2; ks++)
          acc[i][j] = MFMA16(af[i][ks], bf[j][ks], acc[i][j]);
    __builtin_amdgcn_s_setprio(0);
  };
  int nt = K >> 6;
  stage(0, 0);
  stage(64, 1);
  wait_vmcnt<6>();
  __builtin_amdgcn_s_barrier();
  int c0 = 0, c1 = 1, c2 = 2;
  for (int t = 0; t < nt - 2; t++) {
    stage((t + 2) * 64, c2);
    compute(c0);
    wait_vmcnt<6>();
    __builtin_amdgcn_s_barrier();
    int tmp = c0; c0 = c1; c1 = c2; c2 = tmp;
  }
  compute(c0);
  wait_vmcnt<0>();
  __builtin_amdgcn_s_barrier();
  compute(c1);
#pragma unroll
  for (int i = 0; i < 2; i++) {
#pragma unroll
    for (int j = 0; j < 4; j++) {
      int colb = n0 + j * 16 + lr;
      float bv = bias[colb];
#pragma unroll
      for (int r = 0; r < 4; r++) {
        int row = m0 + wm + i * 16 + lg * 4 + r;
        float v = acc[i][j][r] + bv;
        size_t idx = (size_t)row * N + colb;
        if constexpr (EPI == 0) {
          outb[idx] = f2bf(v);
        } else if constexpr (EPI == 1) {
          outf[idx] = v + resid[idx];
        } else {
          float gv = 0.5f * v * (1.0f + erff(v * 0.70710678118654752f));
          outb[idx] = f2bf(gv);
        }
      }
    }
  }
}

// ---------------- causal flash attention (QBLK=128) ----------------
// 4 waves x 32 q-rows (2 q-subtiles of 16), KVBLK=64. Defer-max softmax (T13),
// row-sum via all-ones MFMA, dbuf K/V staging. grid 512: xcd=bid&7, i=bid>>3;
// qt = 15-(i>>2) (big first); bh = xcd*4+(i&3). 50KB LDS -> 3 blocks/CU.
__global__ __launch_bounds__(256) void k_attention(
    const unsigned short* __restrict__ qkv, const unsigned short* __restrict__ Vt,
    unsigned short* __restrict__ out) {
  __shared__ unsigned short lK[2][64 * 64];
  __shared__ unsigned short lV[2][64 * 64];
  __shared__ unsigned short lP[4][32][72];
  int bid = blockIdx.x;
  int i = bid >> 3;
  int qt = 15 - (i >> 2);
  int bh = (bid & 7) * 4 + (i & 3);
  int b = bh >> 4, h = bh & 15;
  int tid = threadIdx.x, lane = tid & 63, w = tid >> 6;
  int lr = lane & 15, lg = lane >> 4;
  const unsigned short* base = qkv + (size_t)b * SEQ * THREE_EMBED + h * HDIM;
  const unsigned short* Kb = base + EMBED;
  const unsigned short* Vb = Vt + (size_t)bh * HDIM * SEQ;
  int q0 = qt * 128 + w * 32;
  bf16x8 qf[2][2];
#pragma unroll
  for (int qs = 0; qs < 2; qs++) {
    int qrow = q0 + qs * 16 + lr;
    qf[qs][0] = *(const bf16x8*)(base + (size_t)qrow * THREE_EMBED + lg * 8);
    qf[qs][1] = *(const bf16x8*)(base + (size_t)qrow * THREE_EMBED + 32 + lg * 8);
  }
  bf16x8 ones;
  {
    short o1 = 0x3F80;  // bf16 1.0
#pragma unroll
    for (int j = 0; j < 8; j++) ones[j] = o1;
  }
  f32x4 o[2][4] = {};
  f32x4 osum[2] = {};
  float m_[2][4];
#pragma unroll
  for (int qs = 0; qs < 2; qs++)
#pragma unroll
    for (int r = 0; r < 4; r++) m_[qs][r] = -INFINITY;
  int srow = lane >> 3;
  int scol = ((lane & 7) ^ (lane >> 3)) * 8;
  const float SCL = 0.125f * 1.4426950408889634f;  // 1/sqrt(64) * log2(e)
  int nkv = 2 * qt + 2;
  auto stage = [&](int kt, int cur) {
#pragma unroll
    for (int c = 0; c < 2; c++) {
      int chunk = w * 2 + c;
      int row = chunk * 8 + srow;
      gload_lds16(Kb + (size_t)(kt * 64 + row) * THREE_EMBED + scol, &lK[cur][chunk * 512]);
      gload_lds16(Vb + (size_t)row * SEQ + kt * 64 + scol, &lV[cur][chunk * 512]);
    }
  };
  stage(0, 0);
  wait_vm0_barrier();
  int cur = 0;
  for (int kt = 0; kt < nkv; kt++) {
    if (kt + 1 < nkv) stage(kt + 1, cur ^ 1);
    if (q0 + 31 >= kt * 64) {  // wave not fully masked
      __builtin_amdgcn_s_setprio(1);
      // ---- QK^T ----
      f32x4 s[2][4];
#pragma unroll
      for (int ct = 0; ct < 4; ct++) {
        int krow = ct * 16 + lr;
        int sw = (krow & 7) << 3;
        bf16x8 k0 = *(const bf16x8*)&lK[cur][krow * 64 + ((lg * 8) ^ sw)];
        bf16x8 k1 = *(const bf16x8*)&lK[cur][krow * 64 + ((32 + lg * 8) ^ sw)];
#pragma unroll
        for (int qs = 0; qs < 2; qs++) {
          f32x4 z = {};
          z = MFMA16(qf[qs][0], k0, z);
          s[qs][ct] = MFMA16(qf[qs][1], k1, z);
        }
      }
      __builtin_amdgcn_s_setprio(0);
      // ---- scale + causal mask + per-lane partial max ----
      bool maskt = (kt * 64 + 63 > q0);
      float pm[2][4];
#pragma unroll
      for (int qs = 0; qs < 2; qs++)
#pragma unroll
        for (int r = 0; r < 4; r++) pm[qs][r] = -INFINITY;
#pragma unroll
      for (int qs = 0; qs < 2; qs++) {
#pragma unroll
        for (int ct = 0; ct < 4; ct++) {
#pragma unroll
          for (int r = 0; r < 4; r++) {
            float sv = s[qs][ct][r] * SCL;
            if (maskt) {
              int kg = kt * 64 + ct * 16 + lr;
              int qg = q0 + qs * 16 + lg * 4 + r;
              if (kg > qg) sv = -INFINITY;
            }
            s[qs][ct][r] = sv;
            pm[qs][r] = fmaxf(pm[qs][r], sv);
          }
        }
      }
      // ---- defer-max (T13): full reduce+rescale only if max grew > 8 ----
      float dm = -INFINITY;
#pragma unroll
      for (int qs = 0; qs < 2; qs++)
#pragma unroll
        for (int r = 0; r < 4; r++) dm = fmaxf(dm, pm[qs][r] - m_[qs][r]);
      if (!__all(dm <= 8.0f)) {
#pragma unroll
        for (int qs = 0; qs < 2; qs++) {
#pragma unroll
          for (int r = 0; r < 4; r++) {
            float mx = pm[qs][r];
            mx = fmaxf(mx, __shfl_xor(mx, 1));
            mx = fmaxf(mx, __shfl_xor(mx, 2));
            mx = fmaxf(mx, __shfl_xor(mx, 4));
            mx = fmaxf(mx, __shfl_xor(mx, 8));
            float mn = fmaxf(m_[qs][r], mx);
            float al = exp2f(m_[qs][r] - mn);
            m_[qs][r] = mn;
            osum[qs][r] *= al;
#pragma unroll
            for (int dt = 0; dt < 4; dt++) o[qs][dt][r] *= al;
          }
        }
      }
      // ---- P = exp2(S - m) -> LDS ----
#pragma unroll
      for (int qs = 0; qs < 2; qs++)
#pragma unroll
        for (int ct = 0; ct < 4; ct++)
#pragma unroll
          for (int r = 0; r < 4; r++)
            lP[w][qs * 16 + lg * 4 + r][ct * 16 + lr] = f2bf(exp2f(s[qs][ct][r] - m_[qs][r]));
      // ---- PV (+ row-sum via all-ones column) ----
      __builtin_amdgcn_s_setprio(1);
#pragma unroll
      for (int ks = 0; ks < 2; ks++) {
        bf16x8 pf[2];
#pragma unroll
        for (int qs = 0; qs < 2; qs++) {
          pf[qs] = *(const bf16x8*)&lP[w][qs * 16 + lr][ks * 32 + lg * 8];
          osum[qs] = MFMA16(pf[qs], ones, osum[qs]);
        }
#pragma unroll
        for (int dt = 0; dt < 4; dt++) {
          int vrow = dt * 16 + lr;
          int sw = (vrow & 7) << 3;
          bf16x8 vf = *(const bf16x8*)&lV[cur][vrow * 64 + ((ks * 32 + lg * 8) ^ sw)];
#pragma unroll
          for (int qs = 0; qs < 2; qs++)
            o[qs][dt] = MFMA16(pf[qs], vf, o[qs][dt]);
        }
      }
      __builtin_amdgcn_s_setprio(0);
    }
    wait_vm0_barrier();
    cur ^= 1;
  }
#pragma unroll
  for (int qs = 0; qs < 2; qs++)
#pragma unroll
    for (int dt = 0; dt < 4; dt++)
#pragma unroll
      for (int r = 0; r < 4; r++) {
        int row = q0 + qs * 16 + lg * 4 + r;
        float val = o[qs][dt][r] / osum[qs][r];
        out[(size_t)(b * SEQ + row) * EMBED + h * HDIM + dt * 16 + lr] = f2bf(val);
      }
}

extern "C" void kernel_launch(void* const* d_in, const int* in_sizes, int n_in,
                              void* d_out, int out_size, void* d_ws, size_t ws_size,
                              hipStream_t stream) {
  const float* x      = (const float*)d_in[0];
  const float* ln1_g  = (const float*)d_in[1];
  const float* ln1_b  = (const float*)d_in[2];
  const float* w_attn = (const float*)d_in[3];
  const float* b_attn = (const float*)d_in[4];
  const float* w_proj = (const float*)d_in[5];
  const float* b_proj = (const float*)d_in[6];
  const float* ln2_g  = (const float*)d_in[7];
  const float* ln2_b  = (const float*)d_in[8];
  const float* w_fc   = (const float*)d_in[9];
  const float* b_fc   = (const float*)d_in[10];
  const float* w_fc2  = (const float*)d_in[11];
  const float* b_fc2  = (const float*)d_in[12];
  float* outp = (float*)d_out;

  char* ws = (char*)d_ws;
  unsigned short* wT_attn = (unsigned short*)(ws);             // [3072][1024] bf16, 6 MB
  unsigned short* wT_proj = (unsigned short*)(ws + 6291456);   // [1024][1024] bf16, 2 MB
  unsigned short* wT_fc   = (unsigned short*)(ws + 8388608);   // [4096][1024] bf16, 8 MB
  unsigned short* wT_fc2  = (unsigned short*)(ws + 16777216);  // [1024][4096] bf16, 8 MB
  unsigned short* buf1    = (unsigned short*)(ws + 25165824);  // 8 MB: xln -> attnout -> x2ln
  float*          x1      = (float*)(ws + 33554432);           // 16 MB fp32 (written after attention)
  unsigned short* Vt      = (unsigned short*)(ws + 33554432);  // 8 MB bf16, dead once attention done
  unsigned short* qkv_h   = (unsigned short*)(ws + 50331648);  // 24 MB qkv -> 32 MB h (48..80 MB)

  dim3 blk(256);
  k_transpose_bf16<<<dim3(3072 / 32, 1024 / 32), blk, 0, stream>>>(w_attn, wT_attn, 1024, 3072);
  k_transpose_bf16<<<dim3(1024 / 32, 1024 / 32), blk, 0, stream>>>(w_proj, wT_proj, 1024, 1024);
  k_transpose_bf16<<<dim3(4096 / 32, 1024 / 32), blk, 0, stream>>>(w_fc, wT_fc, 1024, 4096);
  k_transpose_bf16<<<dim3(1024 / 32, 4096 / 32), blk, 0, stream>>>(w_fc2, wT_fc2, 4096, 1024);
  // LN1: x -> xln (buf1)
  k_layernorm<<<dim3(MTOT), blk, 0, stream>>>(x, ln1_g, ln1_b, buf1);
  // QKV: 256^2 v2, 12x16 = 192 blocks
  k_gemm8<0><<<dim3(THREE_EMBED / 256, MTOT / 256), dim3(512), 0, stream>>>(
      buf1, wT_attn, b_attn, nullptr, nullptr, qkv_h, MTOT, THREE_EMBED, EMBED);
  // V transpose for attention
  k_transpose_v<<<dim3(SEQ / 32, 2 * BATCH * HEADS), blk, 0, stream>>>(qkv_h, Vt);
  // attention -> attnout (buf1): 16 q-tiles x 32 bh = 512 blocks
  k_attention<<<dim3(512), blk, 0, stream>>>(qkv_h, Vt, buf1);
  // proj + residual: narrow BK=64, 16x32 = 512 blocks (overwrites Vt — dead)
  k_gemmN<1><<<dim3(EMBED / 64, MTOT / 128), blk, 0, stream>>>(
      buf1, wT_proj, b_proj, x, x1, nullptr, MTOT, EMBED, EMBED);
  // LN2: x1 -> x2ln (buf1)
  k_layernorm<<<dim3(MTOT), blk, 0, stream>>>(x1, ln2_g, ln2_b, buf1);
  // FC1 + GELU: 256^2 v2, 16x16 = 256 blocks
  k_gemm8<2><<<dim3(4 * EMBED / 256, MTOT / 256), dim3(512), 0, stream>>>(
      buf1, wT_fc, b_fc, nullptr, nullptr, qkv_h, MTOT, 4 * EMBED, EMBED);
  // FC2 + residual -> out: narrow BK=64, 512 blocks
  k_gemmN<1><<<dim3(EMBED / 64, MTOT / 128), blk, 0, stream>>>(
      qkv_h, wT_fc2, b_fc2, x1, outp, nullptr, MTOT, EMBED, 4 * EMBED);
}

// Round 15
// 236.804 us; speedup vs baseline: 1.1212x; 1.1212x over previous
//
#include <hip/hip_runtime.h>

#define EMBED 1024
#define THREE_EMBED 3072
#define HEADS 16
#define HDIM 64
#define SEQ 2048
#define BATCH 2
#define MTOT 4096  // B*T

typedef short bf16x8 __attribute__((ext_vector_type(8)));
typedef float f32x4 __attribute__((ext_vector_type(4)));

#define MFMA16(a, b, c) __builtin_amdgcn_mfma_f32_16x16x32_bf16(a, b, c, 0, 0, 0)

__device__ __forceinline__ unsigned short f2bf(float f) {
  union { float f; unsigned int u; } v; v.f = f;
  unsigned int r = v.u + 0x7fffu + ((v.u >> 16) & 1u);
  return (unsigned short)(r >> 16);
}

// async 16B global->LDS. LDS dest is wave-uniform base + lane*16 (HW semantics).
__device__ __forceinline__ void gload_lds16(const unsigned short* g, unsigned short* l) {
  __builtin_amdgcn_global_load_lds(
      (const __attribute__((address_space(1))) void*)g,
      (__attribute__((address_space(3))) void*)l, 16, 0, 0);
}

__device__ __forceinline__ void wait_vm0_barrier() {
  asm volatile("s_waitcnt vmcnt(0)" ::: "memory");
  __builtin_amdgcn_s_barrier();
}

template <int N>
__device__ __forceinline__ void wait_vmcnt() {
  if constexpr (N == 0) asm volatile("s_waitcnt vmcnt(0)" ::: "memory");
  else if constexpr (N == 1) asm volatile("s_waitcnt vmcnt(1)" ::: "memory");
  else if constexpr (N == 2) asm volatile("s_waitcnt vmcnt(2)" ::: "memory");
  else if constexpr (N == 3) asm volatile("s_waitcnt vmcnt(3)" ::: "memory");
  else if constexpr (N == 4) asm volatile("s_waitcnt vmcnt(4)" ::: "memory");
  else if constexpr (N == 6) asm volatile("s_waitcnt vmcnt(6)" ::: "memory");
  else if constexpr (N == 8) asm volatile("s_waitcnt vmcnt(8)" ::: "memory");
}

__device__ __forceinline__ void open_phase_barrier() {
  __builtin_amdgcn_s_barrier();
  __builtin_amdgcn_sched_barrier(0);  // keep ds_reads below the barrier (rule #18)
}

// ---- merged weight transpose: fp32 [K][N] -> bf16 [N][K], 4 segments, 1 launch ----
// seg0 w_attn 1024x3072 (3072 blk), seg1 w_proj 1024x1024 (1024), seg2 w_fc
// 1024x4096 (4096), seg3 w_fc2 4096x1024 (4096). Total 12288 blocks.
__global__ __launch_bounds__(256) void k_transpose_all(
    const float* __restrict__ w_attn, const float* __restrict__ w_proj,
    const float* __restrict__ w_fc, const float* __restrict__ w_fc2,
    unsigned short* __restrict__ o_attn, unsigned short* __restrict__ o_proj,
    unsigned short* __restrict__ o_fc, unsigned short* __restrict__ o_fc2) {
  __shared__ float t[32][33];
  int bid = blockIdx.x;
  const float* in;
  unsigned short* out;
  int K, N, lid;
  if (bid < 3072) {
    in = w_attn; out = o_attn; K = 1024; N = 3072; lid = bid;
  } else if (bid < 4096) {
    in = w_proj; out = o_proj; K = 1024; N = 1024; lid = bid - 3072;
  } else if (bid < 8192) {
    in = w_fc; out = o_fc; K = 1024; N = 4096; lid = bid - 4096;
  } else {
    in = w_fc2; out = o_fc2; K = 4096; N = 1024; lid = bid - 8192;
  }
  int gx = N >> 5;
  int n0 = (lid % gx) * 32, k0 = (lid / gx) * 32;
  int tx = threadIdx.x & 31, ty = threadIdx.x >> 5;
#pragma unroll
  for (int i = 0; i < 32; i += 8)
    t[ty + i][tx] = in[(size_t)(k0 + ty + i) * N + n0 + tx];
  __syncthreads();
#pragma unroll
  for (int i = 0; i < 32; i += 8)
    out[(size_t)(n0 + ty + i) * K + k0 + tx] = f2bf(t[tx][ty + i]);
}

// ---------------- V transpose: qkv V-part -> Vt[bh][64][2048] bf16 ----------------
__global__ __launch_bounds__(256) void k_transpose_v(
    const unsigned short* __restrict__ qkv, unsigned short* __restrict__ Vt) {
  __shared__ unsigned short t[32][33];
  int tx = threadIdx.x & 31, ty = threadIdx.x >> 5;  // 32 x 8
  int t0 = blockIdx.x * 32;
  int d0 = (blockIdx.y & 1) * 32;
  int bh = blockIdx.y >> 1;
  int b = bh >> 4, h = bh & 15;
  const unsigned short* src = qkv + (size_t)b * SEQ * THREE_EMBED + 2 * EMBED + h * HDIM;
#pragma unroll
  for (int i = 0; i < 32; i += 8)
    t[ty + i][tx] = src[(size_t)(t0 + ty + i) * THREE_EMBED + d0 + tx];
  __syncthreads();
  unsigned short* dst = Vt + (size_t)bh * HDIM * SEQ;
#pragma unroll
  for (int i = 0; i < 32; i += 8)
    dst[(size_t)(d0 + ty + i) * SEQ + t0 + tx] = t[tx][ty + i];
}

// ---------------- layernorm fp32 [4096][1024] -> bf16 ----------------
__global__ __launch_bounds__(256) void k_layernorm(
    const float* __restrict__ x, const float* __restrict__ g,
    const float* __restrict__ b, unsigned short* __restrict__ out) {
  int row = blockIdx.x;
  int tid = threadIdx.x;
  const float4 xv = *(const float4*)(x + (size_t)row * EMBED + tid * 4);
  float s = xv.x + xv.y + xv.z + xv.w;
  float sq = xv.x * xv.x + xv.y * xv.y + xv.z * xv.z + xv.w * xv.w;
#pragma unroll
  for (int off = 1; off < 64; off <<= 1) {
    s += __shfl_xor(s, off);
    sq += __shfl_xor(sq, off);
  }
  __shared__ float red[8];
  int w = tid >> 6;
  if ((tid & 63) == 0) { red[w] = s; red[4 + w] = sq; }
  __syncthreads();
  s = red[0] + red[1] + red[2] + red[3];
  sq = red[4] + red[5] + red[6] + red[7];
  float mu = s * (1.0f / EMBED);
  float var = sq * (1.0f / EMBED) - mu * mu;
  float rs = rsqrtf(var + 1e-5f);
  float xs[4] = {xv.x, xv.y, xv.z, xv.w};
  unsigned short o[4];
#pragma unroll
  for (int c = 0; c < 4; c++) {
    int col = tid * 4 + c;
    o[c] = f2bf((xs[c] - mu) * rs * g[col] + b[col]);
  }
  *(ushort4*)(out + (size_t)row * EMBED + tid * 4) = *(const ushort4*)o;
}

// ======== 256x256 8-wave 4-phase GEMM v2 (register-held operands) ========
// 24 b128 LDS reads per K-tile(64) per wave, uniform vmcnt(4),
// one barrier per phase + sched_barrier(0), tail peeled vmcnt 2->0.
template <int EPI>
__global__ __launch_bounds__(512, 2) void k_gemm8(
    const unsigned short* __restrict__ A, const unsigned short* __restrict__ Bt,
    const float* __restrict__ bias, const float* __restrict__ resid,
    float* __restrict__ outf, unsigned short* __restrict__ outb,
    int M, int N, int K) {
  __shared__ unsigned short lA[2][16384];
  __shared__ unsigned short lB[2][16384];
  int tid = threadIdx.x;
  int nwg = gridDim.x * gridDim.y;
  int bid = blockIdx.y * gridDim.x + blockIdx.x;
  int swz = (bid & 7) * (nwg >> 3) + (bid >> 3);
  int m0 = (swz / gridDim.x) * 256, n0 = (swz % gridDim.x) * 256;
  int lane = tid & 63, w = tid >> 6;
  int lr = lane & 15, lg = lane >> 4;
  int warow = (w >> 2) * 64;  // A row base within a half
  int wbrow = (w & 3) * 32;   // B row base within a half
  int rx = lr & 7;
  int colk[2] = {(lg ^ rx) * 8, ((4 + lg) ^ rx) * 8};
  f32x4 acc[8][4] = {};
  int swzk = ((lane & 7) ^ ((lane >> 3) & 7)) * 8;  // pre-swizzled global col (shorts)
  const unsigned short* gA[2];
  const unsigned short* gB[2];
#pragma unroll
  for (int i = 0; i < 2; i++) {
    int chrow = (w * 2 + i) * 8 + (lane >> 3);
    gA[i] = A + (size_t)(m0 + chrow) * K + swzk;
    gB[i] = Bt + (size_t)(n0 + chrow) * K + swzk;
  }
  int NT = K >> 6;
  auto stageA = [&](int h, int kt, int buf) {
    size_t goff = (size_t)(h * 128) * K + (size_t)kt * 64;
    int lo = h * 8192 + w * 1024;
    gload_lds16(gA[0] + goff, &lA[buf][lo]);
    gload_lds16(gA[1] + goff, &lA[buf][lo + 512]);
  };
  auto stageB = [&](int h, int kt, int buf) {
    size_t goff = (size_t)(h * 128) * K + (size_t)kt * 64;
    int lo = h * 8192 + w * 1024;
    gload_lds16(gB[0] + goff, &lB[buf][lo]);
    gload_lds16(gB[1] + goff, &lB[buf][lo + 512]);
  };
  bf16x8 aX[4][2], aY[4][2], b0[2][2], b1[2][2];
  auto rdA = [&](int buf, int mh, bf16x8 (&dst)[4][2]) {
#pragma unroll
    for (int ii = 0; ii < 4; ii++) {
      int ra = mh * 128 + warow + ii * 16 + lr;
#pragma unroll
      for (int ks = 0; ks < 2; ks++)
        dst[ii][ks] = *(const bf16x8*)&lA[buf][ra * 64 + colk[ks]];
    }
  };
  auto rdB = [&](int buf, int nh, bf16x8 (&dst)[2][2]) {
#pragma unroll
    for (int jj = 0; jj < 2; jj++) {
      int rb = nh * 128 + wbrow + jj * 16 + lr;
#pragma unroll
      for (int ks = 0; ks < 2; ks++)
        dst[jj][ks] = *(const bf16x8*)&lB[buf][rb * 64 + colk[ks]];
    }
  };
  auto mf = [&](int mh, int nh, bf16x8 (&aa)[4][2], bf16x8 (&bb)[2][2]) {
    __builtin_amdgcn_s_setprio(1);
#pragma unroll
    for (int ii = 0; ii < 4; ii++)
#pragma unroll
      for (int jj = 0; jj < 2; jj++)
#pragma unroll
        for (int ks = 0; ks < 2; ks++)
          acc[mh * 4 + ii][nh * 2 + jj] =
              MFMA16(aa[ii][ks], bb[jj][ks], acc[mh * 4 + ii][nh * 2 + jj]);
    __builtin_amdgcn_s_setprio(0);
  };
  stageA(0, 0, 0); stageB(0, 0, 0); stageB(1, 0, 0); stageA(1, 0, 0);
  wait_vmcnt<6>();
  open_phase_barrier();
  rdA(0, 0, aX);
  for (int t = 0; t < NT - 1; t++) {
    int cur = t & 1, nxt = cur ^ 1;
    stageA(0, t + 1, nxt);
    wait_vmcnt<4>();
    open_phase_barrier();
    rdB(cur, 0, b0);
    rdB(cur, 1, b1);
    mf(0, 0, aX, b0);
    stageB(0, t + 1, nxt);
    wait_vmcnt<4>();
    open_phase_barrier();
    rdA(cur, 1, aY);
    mf(0, 1, aX, b1);
    stageB(1, t + 1, nxt);
    wait_vmcnt<4>();
    open_phase_barrier();
    mf(1, 1, aY, b1);
    stageA(1, t + 1, nxt);
    wait_vmcnt<4>();
    open_phase_barrier();
    rdA(nxt, 0, aX);
    mf(1, 0, aY, b0);
  }
  {  // tail tile NT-1 (no staging), tightening drains
    int cur = (NT - 1) & 1;
    wait_vmcnt<2>();
    open_phase_barrier();
    rdB(cur, 0, b0);
    rdB(cur, 1, b1);
    mf(0, 0, aX, b0);
    wait_vmcnt<0>();
    open_phase_barrier();
    rdA(cur, 1, aY);
    mf(0, 1, aX, b1);
    mf(1, 1, aY, b1);
    mf(1, 0, aY, b0);
  }
#pragma unroll
  for (int i = 0; i < 8; i++) {
#pragma unroll
    for (int j = 0; j < 4; j++) {
      int col = n0 + (j >> 1) * 128 + wbrow + (j & 1) * 16 + lr;
      float bv = bias[col];
#pragma unroll
      for (int r = 0; r < 4; r++) {
        int row = m0 + (i >> 2) * 128 + warow + (i & 3) * 16 + lg * 4 + r;
        float v = acc[i][j][r] + bv;
        size_t idx = (size_t)row * N + col;
        if constexpr (EPI == 0) {
          outb[idx] = f2bf(v);
        } else if constexpr (EPI == 1) {
          outf[idx] = v + resid[idx];
        } else {
          float gv = 0.5f * v * (1.0f + erff(v * 0.70710678118654752f));
          outb[idx] = f2bf(gv);
        }
      }
    }
  }
}

// ---- narrow GEMM (BM=128, BN=64, BK=64): 3-buffer counted-vmcnt pipeline ----
template <int EPI>
__global__ __launch_bounds__(256) void k_gemmN(
    const unsigned short* __restrict__ A, const unsigned short* __restrict__ Bt,
    const float* __restrict__ bias, const float* __restrict__ resid,
    float* __restrict__ outf, unsigned short* __restrict__ outb,
    int M, int N, int K) {
  __shared__ unsigned short lA[3][128 * 64];
  __shared__ unsigned short lB[3][64 * 64];
  int tid = threadIdx.x;
  int nwg = gridDim.x * gridDim.y;
  int bid = blockIdx.y * gridDim.x + blockIdx.x;
  int swz = (bid & 7) * (nwg >> 3) + (bid >> 3);
  int m0 = (swz / gridDim.x) * 128, n0 = (swz % gridDim.x) * 64;
  int lane = tid & 63, w = tid >> 6;
  int wm = w * 32;
  int lr = lane & 15, lg = lane >> 4;
  int rx = lr & 7;
  int colk[2] = {(lg ^ rx) * 8, ((4 + lg) ^ rx) * 8};
  f32x4 acc[2][4] = {};
  int swzk = ((lane & 7) ^ ((lane >> 3) & 7)) * 8;  // pre-swizzled global col (shorts)
  const unsigned short* gsrc[6];
  int loff[6];
  bool isa[6];
#pragma unroll
  for (int c0 = 0; c0 < 6; c0++) {
    int c = w * 6 + c0;
    if (c < 16) {
      int row = c * 8 + (lane >> 3);
      gsrc[c0] = A + (size_t)(m0 + row) * K + swzk;
      loff[c0] = c * 512;
      isa[c0] = true;
    } else {
      int row = (c - 16) * 8 + (lane >> 3);
      gsrc[c0] = Bt + (size_t)(n0 + row) * K + swzk;
      loff[c0] = (c - 16) * 512;
      isa[c0] = false;
    }
  }
  auto stage = [&](int k0, int buf) {
#pragma unroll
    for (int c0 = 0; c0 < 6; c0++)
      gload_lds16(gsrc[c0] + k0, isa[c0] ? &lA[buf][loff[c0]] : &lB[buf][loff[c0]]);
  };
  auto compute = [&](int buf) {
    bf16x8 af[2][2], bf[4][2];
#pragma unroll
    for (int i = 0; i < 2; i++)
#pragma unroll
      for (int ks = 0; ks < 2; ks++)
        af[i][ks] = *(const bf16x8*)&lA[buf][(wm + i * 16 + lr) * 64 + colk[ks]];
#pragma unroll
    for (int j = 0; j < 4; j++)
#pragma unroll
      for (int ks = 0; ks < 2; ks++)
        bf[j][ks] = *(const bf16x8*)&lB[buf][(j * 16 + lr) * 64 + colk[ks]];
    __builtin_amdgcn_s_setprio(1);
#pragma unroll
    for (int i = 0; i < 2; i++)
#pragma unroll
      for (int j = 0; j < 4; j++)
#pragma unroll
        for (int ks = 0; ks < 2; ks++)
          acc[i][j] = MFMA16(af[i][ks], bf[j][ks], acc[i][j]);
    __builtin_amdgcn_s_setprio(0);
  };
  int nt = K >> 6;
  stage(0, 0);
  stage(64, 1);
  wait_vmcnt<6>();
  __builtin_amdgcn_s_barrier();
  int c0 = 0, c1 = 1, c2 = 2;
  for (int t = 0; t < nt - 2; t++) {
    stage((t + 2) * 64, c2);
    compute(c0);
    wait_vmcnt<6>();
    __builtin_amdgcn_s_barrier();
    int tmp = c0; c0 = c1; c1 = c2; c2 = tmp;
  }
  compute(c0);
  wait_vmcnt<0>();
  __builtin_amdgcn_s_barrier();
  compute(c1);
#pragma unroll
  for (int i = 0; i < 2; i++) {
#pragma unroll
    for (int j = 0; j < 4; j++) {
      int colb = n0 + j * 16 + lr;
      float bv = bias[colb];
#pragma unroll
      for (int r = 0; r < 4; r++) {
        int row = m0 + wm + i * 16 + lg * 4 + r;
        float v = acc[i][j][r] + bv;
        size_t idx = (size_t)row * N + colb;
        if constexpr (EPI == 0) {
          outb[idx] = f2bf(v);
        } else if constexpr (EPI == 1) {
          outf[idx] = v + resid[idx];
        } else {
          float gv = 0.5f * v * (1.0f + erff(v * 0.70710678118654752f));
          outb[idx] = f2bf(gv);
        }
      }
    }
  }
}

// ---------------- causal flash attention (QBLK=64, R11 champion) ----------------
__global__ __launch_bounds__(256) void k_attention(
    const unsigned short* __restrict__ qkv, const unsigned short* __restrict__ Vt,
    unsigned short* __restrict__ out) {
  __shared__ unsigned short lK[2][64 * 64];
  __shared__ unsigned short lV[2][64 * 64];
  __shared__ unsigned short lP[4][16][72];
  int bid = blockIdx.x;
  int i = bid >> 3;
  int qt = 31 - (i >> 2);
  int bh = (bid & 7) * 4 + (i & 3);
  int b = bh >> 4, h = bh & 15;
  int tid = threadIdx.x, lane = tid & 63, w = tid >> 6;
  int lr = lane & 15, lg = lane >> 4;
  const unsigned short* base = qkv + (size_t)b * SEQ * THREE_EMBED + h * HDIM;
  const unsigned short* Kb = base + EMBED;
  const unsigned short* Vb = Vt + (size_t)bh * HDIM * SEQ;
  int q0 = qt * 64 + w * 16;
  bf16x8 qf[2];
  {
    int qrow = q0 + lr;
    qf[0] = *(const bf16x8*)(base + (size_t)qrow * THREE_EMBED + lg * 8);
    qf[1] = *(const bf16x8*)(base + (size_t)qrow * THREE_EMBED + 32 + lg * 8);
  }
  bf16x8 ones;
  {
    short o1 = 0x3F80;
#pragma unroll
    for (int j = 0; j < 8; j++) ones[j] = o1;
  }
  f32x4 o[4] = {};
  f32x4 osum = {};
  float m_[4] = {-INFINITY, -INFINITY, -INFINITY, -INFINITY};
  int srow = lane >> 3;
  int scol = ((lane & 7) ^ (lane >> 3)) * 8;
  const float SCL = 0.125f * 1.4426950408889634f;
  int nkv = qt + 1;
  auto stage = [&](int kt, int cur) {
#pragma unroll
    for (int c = 0; c < 2; c++) {
      int chunk = w * 2 + c;
      int row = chunk * 8 + srow;
      gload_lds16(Kb + (size_t)(kt * 64 + row) * THREE_EMBED + scol, &lK[cur][chunk * 512]);
      gload_lds16(Vb + (size_t)row * SEQ + kt * 64 + scol, &lV[cur][chunk * 512]);
    }
  };
  stage(0, 0);
  wait_vm0_barrier();
  int cur = 0;
  for (int kt = 0; kt < nkv; kt++) {
    if (kt + 1 < nkv) stage(kt + 1, cur ^ 1);
    __builtin_amdgcn_s_setprio(1);
    f32x4 s[4];
#pragma unroll
    for (int ct = 0; ct < 4; ct++) {
      int krow = ct * 16 + lr;
      int sw = (krow & 7) << 3;
      bf16x8 k0 = *(const bf16x8*)&lK[cur][krow * 64 + ((lg * 8) ^ sw)];
      bf16x8 k1 = *(const bf16x8*)&lK[cur][krow * 64 + ((32 + lg * 8) ^ sw)];
      f32x4 z = {};
      z = MFMA16(qf[0], k0, z);
      s[ct] = MFMA16(qf[1], k1, z);
    }
    __builtin_amdgcn_s_setprio(0);
    bool maskt = (kt * 64 + 63 > q0);
    float pm[4] = {-INFINITY, -INFINITY, -INFINITY, -INFINITY};
#pragma unroll
    for (int ct = 0; ct < 4; ct++) {
#pragma unroll
      for (int r = 0; r < 4; r++) {
        float sv = s[ct][r] * SCL;
        if (maskt) {
          int kg = kt * 64 + ct * 16 + lr;
          int qg = q0 + lg * 4 + r;
          if (kg > qg) sv = -INFINITY;
        }
        s[ct][r] = sv;
        pm[r] = fmaxf(pm[r], sv);
      }
    }
    float dm = fmaxf(fmaxf(pm[0] - m_[0], pm[1] - m_[1]),
                     fmaxf(pm[2] - m_[2], pm[3] - m_[3]));
    if (!__all(dm <= 8.0f)) {
#pragma unroll
      for (int r = 0; r < 4; r++) {
        float mx = pm[r];
        mx = fmaxf(mx, __shfl_xor(mx, 1));
        mx = fmaxf(mx, __shfl_xor(mx, 2));
        mx = fmaxf(mx, __shfl_xor(mx, 4));
        mx = fmaxf(mx, __shfl_xor(mx, 8));
        float mn = fmaxf(m_[r], mx);
        float al = exp2f(m_[r] - mn);
        m_[r] = mn;
        osum[r] *= al;
#pragma unroll
        for (int dt = 0; dt < 4; dt++) o[dt][r] *= al;
      }
    }
#pragma unroll
    for (int ct = 0; ct < 4; ct++)
#pragma unroll
      for (int r = 0; r < 4; r++)
        lP[w][lg * 4 + r][ct * 16 + lr] = f2bf(exp2f(s[ct][r] - m_[r]));
    __builtin_amdgcn_s_setprio(1);
#pragma unroll
    for (int ks = 0; ks < 2; ks++) {
      bf16x8 pf = *(const bf16x8*)&lP[w][lr][ks * 32 + lg * 8];
      osum = MFMA16(pf, ones, osum);
#pragma unroll
      for (int dt = 0; dt < 4; dt++) {
        int vrow = dt * 16 + lr;
        int sw = (vrow & 7) << 3;
        bf16x8 vf = *(const bf16x8*)&lV[cur][vrow * 64 + ((ks * 32 + lg * 8) ^ sw)];
        o[dt] = MFMA16(pf, vf, o[dt]);
      }
    }
    __builtin_amdgcn_s_setprio(0);
    wait_vm0_barrier();
    cur ^= 1;
  }
#pragma unroll
  for (int dt = 0; dt < 4; dt++)
#pragma unroll
    for (int r = 0; r < 4; r++) {
      int row = q0 + lg * 4 + r;
      float val = o[dt][r] / osum[r];
      out[(size_t)(b * SEQ + row) * EMBED + h * HDIM + dt * 16 + lr] = f2bf(val);
    }
}

extern "C" void kernel_launch(void* const* d_in, const int* in_sizes, int n_in,
                              void* d_out, int out_size, void* d_ws, size_t ws_size,
                              hipStream_t stream) {
  const float* x      = (const float*)d_in[0];
  const float* ln1_g  = (const float*)d_in[1];
  const float* ln1_b  = (const float*)d_in[2];
  const float* w_attn = (const float*)d_in[3];
  const float* b_attn = (const float*)d_in[4];
  const float* w_proj = (const float*)d_in[5];
  const float* b_proj = (const float*)d_in[6];
  const float* ln2_g  = (const float*)d_in[7];
  const float* ln2_b  = (const float*)d_in[8];
  const float* w_fc   = (const float*)d_in[9];
  const float* b_fc   = (const float*)d_in[10];
  const float* w_fc2  = (const float*)d_in[11];
  const float* b_fc2  = (const float*)d_in[12];
  float* outp = (float*)d_out;

  char* ws = (char*)d_ws;
  unsigned short* wT_attn = (unsigned short*)(ws);             // [3072][1024] bf16, 6 MB
  unsigned short* wT_proj = (unsigned short*)(ws + 6291456);   // [1024][1024] bf16, 2 MB
  unsigned short* wT_fc   = (unsigned short*)(ws + 8388608);   // [4096][1024] bf16, 8 MB
  unsigned short* wT_fc2  = (unsigned short*)(ws + 16777216);  // [1024][4096] bf16, 8 MB
  unsigned short* buf1    = (unsigned short*)(ws + 25165824);  // 8 MB: xln -> attnout -> x2ln
  float*          x1      = (float*)(ws + 33554432);           // 16 MB fp32 (written after attention)
  unsigned short* Vt      = (unsigned short*)(ws + 33554432);  // 8 MB bf16, dead once attention done
  unsigned short* qkv_h   = (unsigned short*)(ws + 50331648);  // 24 MB qkv -> 32 MB h (48..80 MB)

  dim3 blk(256);
  // all 4 weight transposes in one launch (12288 blocks)
  k_transpose_all<<<dim3(12288), blk, 0, stream>>>(
      w_attn, w_proj, w_fc, w_fc2, wT_attn, wT_proj, wT_fc, wT_fc2);
  // LN1: x -> xln (buf1)
  k_layernorm<<<dim3(MTOT), blk, 0, stream>>>(x, ln1_g, ln1_b, buf1);
  // QKV: 256^2 v2, 12x16 = 192 blocks
  k_gemm8<0><<<dim3(THREE_EMBED / 256, MTOT / 256), dim3(512), 0, stream>>>(
      buf1, wT_attn, b_attn, nullptr, nullptr, qkv_h, MTOT, THREE_EMBED, EMBED);
  // V transpose for attention
  k_transpose_v<<<dim3(SEQ / 32, 2 * BATCH * HEADS), blk, 0, stream>>>(qkv_h, Vt);
  // attention -> attnout (buf1): 32 q-tiles x 32 bh = 1024 blocks
  k_attention<<<dim3(1024), blk, 0, stream>>>(qkv_h, Vt, buf1);
  // proj + residual: narrow BK=64, 16x32 = 512 blocks (overwrites Vt — dead)
  k_gemmN<1><<<dim3(EMBED / 64, MTOT / 128), blk, 0, stream>>>(
      buf1, wT_proj, b_proj, x, x1, nullptr, MTOT, EMBED, EMBED);
  // LN2: x1 -> x2ln (buf1)
  k_layernorm<<<dim3(MTOT), blk, 0, stream>>>(x1, ln2_g, ln2_b, buf1);
  // FC1 + GELU: 256^2 v2, 16x16 = 256 blocks
  k_gemm8<2><<<dim3(4 * EMBED / 256, MTOT / 256), dim3(512), 0, stream>>>(
      buf1, wT_fc, b_fc, nullptr, nullptr, qkv_h, MTOT, 4 * EMBED, EMBED);
  // FC2 + residual -> out: narrow BK=64, 512 blocks
  k_gemmN<1><<<dim3(EMBED / 64, MTOT / 128), blk, 0, stream>>>(
      qkv_h, wT_fc2, b_fc2, x1, outp, nullptr, MTOT, EMBED, 4 * EMBED);
}

// Round 16
// 234.801 us; speedup vs baseline: 1.1307x; 1.0085x over previous
//
#include <hip/hip_runtime.h>

#define EMBED 1024
#define THREE_EMBED 3072
#define HEADS 16
#define HDIM 64
#define SEQ 2048
#define BATCH 2
#define MTOT 4096  // B*T

typedef short bf16x8 __attribute__((ext_vector_type(8)));
typedef float f32x4 __attribute__((ext_vector_type(4)));

#define MFMA16(a, b, c) __builtin_amdgcn_mfma_f32_16x16x32_bf16(a, b, c, 0, 0, 0)

__device__ __forceinline__ unsigned short f2bf(float f) {
  union { float f; unsigned int u; } v; v.f = f;
  unsigned int r = v.u + 0x7fffu + ((v.u >> 16) & 1u);
  return (unsigned short)(r >> 16);
}

__device__ __forceinline__ float bf2f(unsigned short u) {
  union { unsigned int u; float f; } v;
  v.u = (unsigned int)u << 16;
  return v.f;
}

// async 16B global->LDS. LDS dest is wave-uniform base + lane*16 (HW semantics).
__device__ __forceinline__ void gload_lds16(const unsigned short* g, unsigned short* l) {
  __builtin_amdgcn_global_load_lds(
      (const __attribute__((address_space(1))) void*)g,
      (__attribute__((address_space(3))) void*)l, 16, 0, 0);
}

__device__ __forceinline__ void wait_vm0_barrier() {
  asm volatile("s_waitcnt vmcnt(0)" ::: "memory");
  __builtin_amdgcn_s_barrier();
}

template <int N>
__device__ __forceinline__ void wait_vmcnt() {
  if constexpr (N == 0) asm volatile("s_waitcnt vmcnt(0)" ::: "memory");
  else if constexpr (N == 1) asm volatile("s_waitcnt vmcnt(1)" ::: "memory");
  else if constexpr (N == 2) asm volatile("s_waitcnt vmcnt(2)" ::: "memory");
  else if constexpr (N == 3) asm volatile("s_waitcnt vmcnt(3)" ::: "memory");
  else if constexpr (N == 4) asm volatile("s_waitcnt vmcnt(4)" ::: "memory");
  else if constexpr (N == 6) asm volatile("s_waitcnt vmcnt(6)" ::: "memory");
  else if constexpr (N == 8) asm volatile("s_waitcnt vmcnt(8)" ::: "memory");
}

// after-barrier LDS fence: wait all ds_reads issued pre-barrier, pin MFMA below (rule #18)
__device__ __forceinline__ void lds_fence() {
  asm volatile("s_waitcnt lgkmcnt(0)" ::: "memory");
  __builtin_amdgcn_sched_barrier(0);
}

// ---- merged weight transpose: fp32 [K][N] -> bf16 [N][K], 4 segments, 1 launch ----
__global__ __launch_bounds__(256) void k_transpose_all(
    const float* __restrict__ w_attn, const float* __restrict__ w_proj,
    const float* __restrict__ w_fc, const float* __restrict__ w_fc2,
    unsigned short* __restrict__ o_attn, unsigned short* __restrict__ o_proj,
    unsigned short* __restrict__ o_fc, unsigned short* __restrict__ o_fc2) {
  __shared__ float t[32][33];
  int bid = blockIdx.x;
  const float* in;
  unsigned short* out;
  int K, N, lid;
  if (bid < 3072) {
    in = w_attn; out = o_attn; K = 1024; N = 3072; lid = bid;
  } else if (bid < 4096) {
    in = w_proj; out = o_proj; K = 1024; N = 1024; lid = bid - 3072;
  } else if (bid < 8192) {
    in = w_fc; out = o_fc; K = 1024; N = 4096; lid = bid - 4096;
  } else {
    in = w_fc2; out = o_fc2; K = 4096; N = 1024; lid = bid - 8192;
  }
  int gx = N >> 5;
  int n0 = (lid % gx) * 32, k0 = (lid / gx) * 32;
  int tx = threadIdx.x & 31, ty = threadIdx.x >> 5;
#pragma unroll
  for (int i = 0; i < 32; i += 8)
    t[ty + i][tx] = in[(size_t)(k0 + ty + i) * N + n0 + tx];
  __syncthreads();
#pragma unroll
  for (int i = 0; i < 32; i += 8)
    out[(size_t)(n0 + ty + i) * K + k0 + tx] = f2bf(t[tx][ty + i]);
}

// ---------------- V transpose: qkv V-part -> Vt[bh][64][2048] bf16 ----------------
__global__ __launch_bounds__(256) void k_transpose_v(
    const unsigned short* __restrict__ qkv, unsigned short* __restrict__ Vt) {
  __shared__ unsigned short t[32][33];
  int tx = threadIdx.x & 31, ty = threadIdx.x >> 5;  // 32 x 8
  int t0 = blockIdx.x * 32;
  int d0 = (blockIdx.y & 1) * 32;
  int bh = blockIdx.y >> 1;
  int b = bh >> 4, h = bh & 15;
  const unsigned short* src = qkv + (size_t)b * SEQ * THREE_EMBED + 2 * EMBED + h * HDIM;
#pragma unroll
  for (int i = 0; i < 32; i += 8)
    t[ty + i][tx] = src[(size_t)(t0 + ty + i) * THREE_EMBED + d0 + tx];
  __syncthreads();
  unsigned short* dst = Vt + (size_t)bh * HDIM * SEQ;
#pragma unroll
  for (int i = 0; i < 32; i += 8)
    dst[(size_t)(d0 + ty + i) * SEQ + t0 + tx] = t[tx][ty + i];
}

// ---------------- layernorm fp32 [4096][1024] -> bf16 ----------------
__global__ __launch_bounds__(256) void k_layernorm(
    const float* __restrict__ x, const float* __restrict__ g,
    const float* __restrict__ b, unsigned short* __restrict__ out) {
  int row = blockIdx.x;
  int tid = threadIdx.x;
  const float4 xv = *(const float4*)(x + (size_t)row * EMBED + tid * 4);
  float s = xv.x + xv.y + xv.z + xv.w;
  float sq = xv.x * xv.x + xv.y * xv.y + xv.z * xv.z + xv.w * xv.w;
#pragma unroll
  for (int off = 1; off < 64; off <<= 1) {
    s += __shfl_xor(s, off);
    sq += __shfl_xor(sq, off);
  }
  __shared__ float red[8];
  int w = tid >> 6;
  if ((tid & 63) == 0) { red[w] = s; red[4 + w] = sq; }
  __syncthreads();
  s = red[0] + red[1] + red[2] + red[3];
  sq = red[4] + red[5] + red[6] + red[7];
  float mu = s * (1.0f / EMBED);
  float var = sq * (1.0f / EMBED) - mu * mu;
  float rs = rsqrtf(var + 1e-5f);
  float xs[4] = {xv.x, xv.y, xv.z, xv.w};
  unsigned short o[4];
#pragma unroll
  for (int c = 0; c < 4; c++) {
    int col = tid * 4 + c;
    o[c] = f2bf((xs[c] - mu) * rs * g[col] + b[col]);
  }
  *(ushort4*)(out + (size_t)row * EMBED + tid * 4) = *(const ushort4*)o;
}

// ======== 256x256 8-wave 4-phase GEMM v3 (m201-skeleton phases) ========
// Per phase: {ds_read(this phase's operands, published >=1 barrier ago);
// stage-group; vmcnt(4); barrier; lgkmcnt(0)+sched_barrier; 16 MFMA}.
// Stage groups: G1={A0',B0'}@p1 (4 loads), G2={B1',A1'}@p3 (4 loads).
// Publish audit: b0@p1 <- G1(t-1) pub p3(t-1); b1,aY@p2 <- G2(t-1) pub p1(t);
// aX@p4 <- G1(t) pub p3(t). Flight = 2 phases. WAR distances >= 4 phases.
template <int EPI>
__global__ __launch_bounds__(512, 2) void k_gemm8(
    const unsigned short* __restrict__ A, const unsigned short* __restrict__ Bt,
    const float* __restrict__ bias, const float* __restrict__ resid,
    float* __restrict__ outf, unsigned short* __restrict__ outb,
    int M, int N, int K) {
  __shared__ unsigned short lA[2][16384];
  __shared__ unsigned short lB[2][16384];
  int tid = threadIdx.x;
  int nwg = gridDim.x * gridDim.y;
  int bid = blockIdx.y * gridDim.x + blockIdx.x;
  int swz = (bid & 7) * (nwg >> 3) + (bid >> 3);
  int m0 = (swz / gridDim.x) * 256, n0 = (swz % gridDim.x) * 256;
  int lane = tid & 63, w = tid >> 6;
  int lr = lane & 15, lg = lane >> 4;
  int warow = (w >> 2) * 64;  // A row base within a half
  int wbrow = (w & 3) * 32;   // B row base within a half
  int rx = lr & 7;
  int colk[2] = {(lg ^ rx) * 8, ((4 + lg) ^ rx) * 8};
  f32x4 acc[8][4] = {};
  int swzk = ((lane & 7) ^ ((lane >> 3) & 7)) * 8;  // pre-swizzled global col (shorts)
  const unsigned short* gA[2];
  const unsigned short* gB[2];
#pragma unroll
  for (int i = 0; i < 2; i++) {
    int chrow = (w * 2 + i) * 8 + (lane >> 3);
    gA[i] = A + (size_t)(m0 + chrow) * K + swzk;
    gB[i] = Bt + (size_t)(n0 + chrow) * K + swzk;
  }
  int NT = K >> 6;
  auto stageA = [&](int h, int kt, int buf) {
    size_t goff = (size_t)(h * 128) * K + (size_t)kt * 64;
    int lo = h * 8192 + w * 1024;
    gload_lds16(gA[0] + goff, &lA[buf][lo]);
    gload_lds16(gA[1] + goff, &lA[buf][lo + 512]);
  };
  auto stageB = [&](int h, int kt, int buf) {
    size_t goff = (size_t)(h * 128) * K + (size_t)kt * 64;
    int lo = h * 8192 + w * 1024;
    gload_lds16(gB[0] + goff, &lB[buf][lo]);
    gload_lds16(gB[1] + goff, &lB[buf][lo + 512]);
  };
  bf16x8 aX[4][2], aY[4][2], b0[2][2], b1[2][2];
  auto rdA = [&](int buf, int mh, bf16x8 (&dst)[4][2]) {
#pragma unroll
    for (int ii = 0; ii < 4; ii++) {
      int ra = mh * 128 + warow + ii * 16 + lr;
#pragma unroll
      for (int ks = 0; ks < 2; ks++)
        dst[ii][ks] = *(const bf16x8*)&lA[buf][ra * 64 + colk[ks]];
    }
  };
  auto rdB = [&](int buf, int nh, bf16x8 (&dst)[2][2]) {
#pragma unroll
    for (int jj = 0; jj < 2; jj++) {
      int rb = nh * 128 + wbrow + jj * 16 + lr;
#pragma unroll
      for (int ks = 0; ks < 2; ks++)
        dst[jj][ks] = *(const bf16x8*)&lB[buf][rb * 64 + colk[ks]];
    }
  };
  auto mf = [&](int mh, int nh, bf16x8 (&aa)[4][2], bf16x8 (&bb)[2][2]) {
    __builtin_amdgcn_s_setprio(1);
#pragma unroll
    for (int ii = 0; ii < 4; ii++)
#pragma unroll
      for (int jj = 0; jj < 2; jj++)
#pragma unroll
        for (int ks = 0; ks < 2; ks++)
          acc[mh * 4 + ii][nh * 2 + jj] =
              MFMA16(aa[ii][ks], bb[jj][ks], acc[mh * 4 + ii][nh * 2 + jj]);
    __builtin_amdgcn_s_setprio(0);
  };
  // prologue: G1(0)+G2(0), confirm G1, publish, prefetch-read aX(A0 of tile 0)
  stageA(0, 0, 0); stageB(0, 0, 0);   // G1(0)
  stageB(1, 0, 0); stageA(1, 0, 0);   // G2(0)
  wait_vmcnt<4>();
  __builtin_amdgcn_s_barrier();
  rdA(0, 0, aX);
  for (int t = 0; t < NT - 1; t++) {
    int cur = t & 1, nxt = cur ^ 1;
    // p1: read b0 (pub p3(t-1)); stage G1(t+1); confirm G2(t-1); mf(0,0)
    rdB(cur, 0, b0);
    stageA(0, t + 1, nxt); stageB(0, t + 1, nxt);
    wait_vmcnt<4>();
    __builtin_amdgcn_s_barrier();
    lds_fence();
    mf(0, 0, aX, b0);
    // p2: read b1,aY (pub p1); mf(0,1)
    rdB(cur, 1, b1);
    rdA(cur, 1, aY);
    __builtin_amdgcn_s_barrier();
    lds_fence();
    mf(0, 1, aX, b1);
    // p3: stage G2(t+1); confirm G1(t); mf(1,1)
    stageB(1, t + 1, nxt); stageA(1, t + 1, nxt);
    wait_vmcnt<4>();
    __builtin_amdgcn_s_barrier();
    lds_fence();
    mf(1, 1, aY, b1);
    // p4: prefetch-read aX = A0(t+1) (pub p3); mf(1,0)
    rdA(nxt, 0, aX);
    __builtin_amdgcn_s_barrier();
    lds_fence();
    mf(1, 0, aY, b0);
  }
  {  // tail tile NT-1: no staging; drain remaining G2(NT-2) then finish
    int cur = (NT - 1) & 1;
    rdB(cur, 0, b0);                 // pub p3(NT-2)
    wait_vmcnt<0>();
    __builtin_amdgcn_s_barrier();
    lds_fence();
    mf(0, 0, aX, b0);
    rdB(cur, 1, b1);
    rdA(cur, 1, aY);
    lds_fence();
    mf(0, 1, aX, b1);
    mf(1, 1, aY, b1);
    mf(1, 0, aY, b0);
  }
#pragma unroll
  for (int i = 0; i < 8; i++) {
#pragma unroll
    for (int j = 0; j < 4; j++) {
      int col = n0 + (j >> 1) * 128 + wbrow + (j & 1) * 16 + lr;
      float bv = bias[col];
#pragma unroll
      for (int r = 0; r < 4; r++) {
        int row = m0 + (i >> 2) * 128 + warow + (i & 3) * 16 + lg * 4 + r;
        float v = acc[i][j][r] + bv;
        size_t idx = (size_t)row * N + col;
        if constexpr (EPI == 0) {
          outb[idx] = f2bf(v);
        } else if constexpr (EPI == 1) {
          outf[idx] = v + resid[idx];
        } else {
          float gv = 0.5f * v * (1.0f + erff(v * 0.70710678118654752f));
          outb[idx] = f2bf(gv);
        }
      }
    }
  }
}

// ---- narrow GEMM (BM=128, BN=64, BK=64): 3-buffer counted-vmcnt pipeline ----
template <int EPI>
__global__ __launch_bounds__(256) void k_gemmN(
    const unsigned short* __restrict__ A, const unsigned short* __restrict__ Bt,
    const float* __restrict__ bias, const float* __restrict__ resid,
    float* __restrict__ outf, unsigned short* __restrict__ outb,
    int M, int N, int K) {
  __shared__ unsigned short lA[3][128 * 64];
  __shared__ unsigned short lB[3][64 * 64];
  int tid = threadIdx.x;
  int nwg = gridDim.x * gridDim.y;
  int bid = blockIdx.y * gridDim.x + blockIdx.x;
  int swz = (bid & 7) * (nwg >> 3) + (bid >> 3);
  int m0 = (swz / gridDim.x) * 128, n0 = (swz % gridDim.x) * 64;
  int lane = tid & 63, w = tid >> 6;
  int wm = w * 32;
  int lr = lane & 15, lg = lane >> 4;
  int rx = lr & 7;
  int colk[2] = {(lg ^ rx) * 8, ((4 + lg) ^ rx) * 8};
  f32x4 acc[2][4] = {};
  int swzk = ((lane & 7) ^ ((lane >> 3) & 7)) * 8;  // pre-swizzled global col (shorts)
  const unsigned short* gsrc[6];
  int loff[6];
  bool isa[6];
#pragma unroll
  for (int c0 = 0; c0 < 6; c0++) {
    int c = w * 6 + c0;
    if (c < 16) {
      int row = c * 8 + (lane >> 3);
      gsrc[c0] = A + (size_t)(m0 + row) * K + swzk;
      loff[c0] = c * 512;
      isa[c0] = true;
    } else {
      int row = (c - 16) * 8 + (lane >> 3);
      gsrc[c0] = Bt + (size_t)(n0 + row) * K + swzk;
      loff[c0] = (c - 16) * 512;
      isa[c0] = false;
    }
  }
  auto stage = [&](int k0, int buf) {
#pragma unroll
    for (int c0 = 0; c0 < 6; c0++)
      gload_lds16(gsrc[c0] + k0, isa[c0] ? &lA[buf][loff[c0]] : &lB[buf][loff[c0]]);
  };
  auto compute = [&](int buf) {
    bf16x8 af[2][2], bf[4][2];
#pragma unroll
    for (int i = 0; i < 2; i++)
#pragma unroll
      for (int ks = 0; ks < 2; ks++)
        af[i][ks] = *(const bf16x8*)&lA[buf][(wm + i * 16 + lr) * 64 + colk[ks]];
#pragma unroll
    for (int j = 0; j < 4; j++)
#pragma unroll
      for (int ks = 0; ks < 2; ks++)
        bf[j][ks] = *(const bf16x8*)&lB[buf][(j * 16 + lr) * 64 + colk[ks]];
    __builtin_amdgcn_s_setprio(1);
#pragma unroll
    for (int i = 0; i < 2; i++)
#pragma unroll
      for (int j = 0; j < 4; j++)
#pragma unroll
        for (int ks = 0; ks < 2; ks++)
          acc[i][j] = MFMA16(af[i][ks], bf[j][ks], acc[i][j]);
    __builtin_amdgcn_s_setprio(0);
  };
  int nt = K >> 6;
  stage(0, 0);
  stage(64, 1);
  wait_vmcnt<6>();
  __builtin_amdgcn_s_barrier();
  int c0 = 0, c1 = 1, c2 = 2;
  for (int t = 0; t < nt - 2; t++) {
    stage((t + 2) * 64, c2);
    compute(c0);
    wait_vmcnt<6>();
    __builtin_amdgcn_s_barrier();
    int tmp = c0; c0 = c1; c1 = c2; c2 = tmp;
  }
  compute(c0);
  wait_vmcnt<0>();
  __builtin_amdgcn_s_barrier();
  compute(c1);
#pragma unroll
  for (int i = 0; i < 2; i++) {
#pragma unroll
    for (int j = 0; j < 4; j++) {
      int colb = n0 + j * 16 + lr;
      float bv = bias[colb];
#pragma unroll
      for (int r = 0; r < 4; r++) {
        int row = m0 + wm + i * 16 + lg * 4 + r;
        float v = acc[i][j][r] + bv;
        size_t idx = (size_t)row * N + colb;
        if constexpr (EPI == 0) {
          outb[idx] = f2bf(v);
        } else if constexpr (EPI == 1) {
          outf[idx] = v + resid[idx];
        } else {
          float gv = 0.5f * v * (1.0f + erff(v * 0.70710678118654752f));
          outb[idx] = f2bf(gv);
        }
      }
    }
  }
}

// ---------------- causal flash attention (QBLK=64) ----------------
// Q pre-scaled by 1/8*log2e at load (kills 16 v_mul/iter); lP pitch 74
// (pf ds_read_b128 bank = (5*lr+4*lg)%32 -> ~2-way instead of 8-way).
__global__ __launch_bounds__(256) void k_attention(
    const unsigned short* __restrict__ qkv, const unsigned short* __restrict__ Vt,
    unsigned short* __restrict__ out) {
  __shared__ unsigned short lK[2][64 * 64];
  __shared__ unsigned short lV[2][64 * 64];
  __shared__ unsigned short lP[4][16][74];
  int bid = blockIdx.x;
  int i = bid >> 3;
  int qt = 31 - (i >> 2);
  int bh = (bid & 7) * 4 + (i & 3);
  int b = bh >> 4, h = bh & 15;
  int tid = threadIdx.x, lane = tid & 63, w = tid >> 6;
  int lr = lane & 15, lg = lane >> 4;
  const unsigned short* base = qkv + (size_t)b * SEQ * THREE_EMBED + h * HDIM;
  const unsigned short* Kb = base + EMBED;
  const unsigned short* Vb = Vt + (size_t)bh * HDIM * SEQ;
  int q0 = qt * 64 + w * 16;
  const float SCL = 0.125f * 1.4426950408889634f;  // 1/sqrt(64) * log2(e)
  bf16x8 qf[2];
  {
    int qrow = q0 + lr;
    bf16x8 r0 = *(const bf16x8*)(base + (size_t)qrow * THREE_EMBED + lg * 8);
    bf16x8 r1 = *(const bf16x8*)(base + (size_t)qrow * THREE_EMBED + 32 + lg * 8);
#pragma unroll
    for (int j = 0; j < 8; j++) {
      qf[0][j] = (short)f2bf(bf2f((unsigned short)r0[j]) * SCL);
      qf[1][j] = (short)f2bf(bf2f((unsigned short)r1[j]) * SCL);
    }
  }
  bf16x8 ones;
  {
    short o1 = 0x3F80;
#pragma unroll
    for (int j = 0; j < 8; j++) ones[j] = o1;
  }
  f32x4 o[4] = {};
  f32x4 osum = {};
  float m_[4] = {-INFINITY, -INFINITY, -INFINITY, -INFINITY};
  int srow = lane >> 3;
  int scol = ((lane & 7) ^ (lane >> 3)) * 8;
  int nkv = qt + 1;
  auto stage = [&](int kt, int cur) {
#pragma unroll
    for (int c = 0; c < 2; c++) {
      int chunk = w * 2 + c;
      int row = chunk * 8 + srow;
      gload_lds16(Kb + (size_t)(kt * 64 + row) * THREE_EMBED + scol, &lK[cur][chunk * 512]);
      gload_lds16(Vb + (size_t)row * SEQ + kt * 64 + scol, &lV[cur][chunk * 512]);
    }
  };
  stage(0, 0);
  wait_vm0_barrier();
  int cur = 0;
  for (int kt = 0; kt < nkv; kt++) {
    if (kt + 1 < nkv) stage(kt + 1, cur ^ 1);
    __builtin_amdgcn_s_setprio(1);
    f32x4 s[4];
#pragma unroll
    for (int ct = 0; ct < 4; ct++) {
      int krow = ct * 16 + lr;
      int sw = (krow & 7) << 3;
      bf16x8 k0 = *(const bf16x8*)&lK[cur][krow * 64 + ((lg * 8) ^ sw)];
      bf16x8 k1 = *(const bf16x8*)&lK[cur][krow * 64 + ((32 + lg * 8) ^ sw)];
      f32x4 z = {};
      z = MFMA16(qf[0], k0, z);
      s[ct] = MFMA16(qf[1], k1, z);
    }
    __builtin_amdgcn_s_setprio(0);
    bool maskt = (kt * 64 + 63 > q0);
    float pm[4] = {-INFINITY, -INFINITY, -INFINITY, -INFINITY};
#pragma unroll
    for (int ct = 0; ct < 4; ct++) {
#pragma unroll
      for (int r = 0; r < 4; r++) {
        float sv = s[ct][r];  // SCL pre-folded into Q
        if (maskt) {
          int kg = kt * 64 + ct * 16 + lr;
          int qg = q0 + lg * 4 + r;
          if (kg > qg) sv = -INFINITY;
        }
        s[ct][r] = sv;
        pm[r] = fmaxf(pm[r], sv);
      }
    }
    float dm = fmaxf(fmaxf(pm[0] - m_[0], pm[1] - m_[1]),
                     fmaxf(pm[2] - m_[2], pm[3] - m_[3]));
    if (!__all(dm <= 8.0f)) {
#pragma unroll
      for (int r = 0; r < 4; r++) {
        float mx = pm[r];
        mx = fmaxf(mx, __shfl_xor(mx, 1));
        mx = fmaxf(mx, __shfl_xor(mx, 2));
        mx = fmaxf(mx, __shfl_xor(mx, 4));
        mx = fmaxf(mx, __shfl_xor(mx, 8));
        float mn = fmaxf(m_[r], mx);
        float al = exp2f(m_[r] - mn);
        m_[r] = mn;
        osum[r] *= al;
#pragma unroll
        for (int dt = 0; dt < 4; dt++) o[dt][r] *= al;
      }
    }
#pragma unroll
    for (int ct = 0; ct < 4; ct++)
#pragma unroll
      for (int r = 0; r < 4; r++)
        lP[w][lg * 4 + r][ct * 16 + lr] = f2bf(exp2f(s[ct][r] - m_[r]));
    __builtin_amdgcn_s_setprio(1);
#pragma unroll
    for (int ks = 0; ks < 2; ks++) {
      bf16x8 pf = *(const bf16x8*)&lP[w][lr][ks * 32 + lg * 8];
      osum = MFMA16(pf, ones, osum);
#pragma unroll
      for (int dt = 0; dt < 4; dt++) {
        int vrow = dt * 16 + lr;
        int sw = (vrow & 7) << 3;
        bf16x8 vf = *(const bf16x8*)&lV[cur][vrow * 64 + ((ks * 32 + lg * 8) ^ sw)];
        o[dt] = MFMA16(pf, vf, o[dt]);
      }
    }
    __builtin_amdgcn_s_setprio(0);
    wait_vm0_barrier();
    cur ^= 1;
  }
#pragma unroll
  for (int dt = 0; dt < 4; dt++)
#pragma unroll
    for (int r = 0; r < 4; r++) {
      int row = q0 + lg * 4 + r;
      float val = o[dt][r] / osum[r];
      out[(size_t)(b * SEQ + row) * EMBED + h * HDIM + dt * 16 + lr] = f2bf(val);
    }
}

extern "C" void kernel_launch(void* const* d_in, const int* in_sizes, int n_in,
                              void* d_out, int out_size, void* d_ws, size_t ws_size,
                              hipStream_t stream) {
  const float* x      = (const float*)d_in[0];
  const float* ln1_g  = (const float*)d_in[1];
  const float* ln1_b  = (const float*)d_in[2];
  const float* w_attn = (const float*)d_in[3];
  const float* b_attn = (const float*)d_in[4];
  const float* w_proj = (const float*)d_in[5];
  const float* b_proj = (const float*)d_in[6];
  const float* ln2_g  = (const float*)d_in[7];
  const float* ln2_b  = (const float*)d_in[8];
  const float* w_fc   = (const float*)d_in[9];
  const float* b_fc   = (const float*)d_in[10];
  const float* w_fc2  = (const float*)d_in[11];
  const float* b_fc2  = (const float*)d_in[12];
  float* outp = (float*)d_out;

  char* ws = (char*)d_ws;
  unsigned short* wT_attn = (unsigned short*)(ws);             // [3072][1024] bf16, 6 MB
  unsigned short* wT_proj = (unsigned short*)(ws + 6291456);   // [1024][1024] bf16, 2 MB
  unsigned short* wT_fc   = (unsigned short*)(ws + 8388608);   // [4096][1024] bf16, 8 MB
  unsigned short* wT_fc2  = (unsigned short*)(ws + 16777216);  // [1024][4096] bf16, 8 MB
  unsigned short* buf1    = (unsigned short*)(ws + 25165824);  // 8 MB: xln -> attnout -> x2ln
  float*          x1      = (float*)(ws + 33554432);           // 16 MB fp32 (written after attention)
  unsigned short* Vt      = (unsigned short*)(ws + 33554432);  // 8 MB bf16, dead once attention done
  unsigned short* qkv_h   = (unsigned short*)(ws + 50331648);  // 24 MB qkv -> 32 MB h (48..80 MB)

  dim3 blk(256);
  // all 4 weight transposes in one launch (12288 blocks)
  k_transpose_all<<<dim3(12288), blk, 0, stream>>>(
      w_attn, w_proj, w_fc, w_fc2, wT_attn, wT_proj, wT_fc, wT_fc2);
  // LN1: x -> xln (buf1)
  k_layernorm<<<dim3(MTOT), blk, 0, stream>>>(x, ln1_g, ln1_b, buf1);
  // QKV: 256^2 v3, 12x16 = 192 blocks
  k_gemm8<0><<<dim3(THREE_EMBED / 256, MTOT / 256), dim3(512), 0, stream>>>(
      buf1, wT_attn, b_attn, nullptr, nullptr, qkv_h, MTOT, THREE_EMBED, EMBED);
  // V transpose for attention
  k_transpose_v<<<dim3(SEQ / 32, 2 * BATCH * HEADS), blk, 0, stream>>>(qkv_h, Vt);
  // attention -> attnout (buf1): 32 q-tiles x 32 bh = 1024 blocks
  k_attention<<<dim3(1024), blk, 0, stream>>>(qkv_h, Vt, buf1);
  // proj + residual: narrow BK=64, 16x32 = 512 blocks (overwrites Vt — dead)
  k_gemmN<1><<<dim3(EMBED / 64, MTOT / 128), blk, 0, stream>>>(
      buf1, wT_proj, b_proj, x, x1, nullptr, MTOT, EMBED, EMBED);
  // LN2: x1 -> x2ln (buf1)
  k_layernorm<<<dim3(MTOT), blk, 0, stream>>>(x1, ln2_g, ln2_b, buf1);
  // FC1 + GELU: 256^2 v3, 16x16 = 256 blocks
  k_gemm8<2><<<dim3(4 * EMBED / 256, MTOT / 256), dim3(512), 0, stream>>>(
      buf1, wT_fc, b_fc, nullptr, nullptr, qkv_h, MTOT, 4 * EMBED, EMBED);
  // FC2 + residual -> out: narrow BK=64, 512 blocks
  k_gemmN<1><<<dim3(EMBED / 64, MTOT / 128), blk, 0, stream>>>(
      qkv_h, wT_fc2, b_fc2, x1, outp, nullptr, MTOT, EMBED, 4 * EMBED);
}

// Round 17
// 233.043 us; speedup vs baseline: 1.1393x; 1.0075x over previous
//
#include <hip/hip_runtime.h>

#define EMBED 1024
#define THREE_EMBED 3072
#define HEADS 16
#define HDIM 64
#define SEQ 2048
#define BATCH 2
#define MTOT 4096  // B*T

typedef short bf16x8 __attribute__((ext_vector_type(8)));
typedef float f32x4 __attribute__((ext_vector_type(4)));

#define MFMA16(a, b, c) __builtin_amdgcn_mfma_f32_16x16x32_bf16(a, b, c, 0, 0, 0)

__device__ __forceinline__ unsigned short f2bf(float f) {
  union { float f; unsigned int u; } v; v.f = f;
  unsigned int r = v.u + 0x7fffu + ((v.u >> 16) & 1u);
  return (unsigned short)(r >> 16);
}

__device__ __forceinline__ float bf2f(unsigned short u) {
  union { unsigned int u; float f; } v;
  v.u = (unsigned int)u << 16;
  return v.f;
}

// async 16B global->LDS. LDS dest is wave-uniform base + lane*16 (HW semantics).
__device__ __forceinline__ void gload_lds16(const unsigned short* g, unsigned short* l) {
  __builtin_amdgcn_global_load_lds(
      (const __attribute__((address_space(1))) void*)g,
      (__attribute__((address_space(3))) void*)l, 16, 0, 0);
}

__device__ __forceinline__ void wait_vm0_barrier() {
  asm volatile("s_waitcnt vmcnt(0)" ::: "memory");
  __builtin_amdgcn_s_barrier();
}

template <int N>
__device__ __forceinline__ void wait_vmcnt() {
  if constexpr (N == 0) asm volatile("s_waitcnt vmcnt(0)" ::: "memory");
  else if constexpr (N == 1) asm volatile("s_waitcnt vmcnt(1)" ::: "memory");
  else if constexpr (N == 2) asm volatile("s_waitcnt vmcnt(2)" ::: "memory");
  else if constexpr (N == 3) asm volatile("s_waitcnt vmcnt(3)" ::: "memory");
  else if constexpr (N == 4) asm volatile("s_waitcnt vmcnt(4)" ::: "memory");
  else if constexpr (N == 6) asm volatile("s_waitcnt vmcnt(6)" ::: "memory");
  else if constexpr (N == 8) asm volatile("s_waitcnt vmcnt(8)" ::: "memory");
}

// after-barrier LDS fence: wait all ds_reads issued pre-barrier, pin MFMA below (rule #18)
__device__ __forceinline__ void lds_fence() {
  asm volatile("s_waitcnt lgkmcnt(0)" ::: "memory");
  __builtin_amdgcn_sched_barrier(0);
}

// ---- merged weight transpose: fp32 [K][N] -> bf16 [N][K], 4 segments, 1 launch ----
__global__ __launch_bounds__(256) void k_transpose_all(
    const float* __restrict__ w_attn, const float* __restrict__ w_proj,
    const float* __restrict__ w_fc, const float* __restrict__ w_fc2,
    unsigned short* __restrict__ o_attn, unsigned short* __restrict__ o_proj,
    unsigned short* __restrict__ o_fc, unsigned short* __restrict__ o_fc2) {
  __shared__ float t[32][33];
  int bid = blockIdx.x;
  const float* in;
  unsigned short* out;
  int K, N, lid;
  if (bid < 3072) {
    in = w_attn; out = o_attn; K = 1024; N = 3072; lid = bid;
  } else if (bid < 4096) {
    in = w_proj; out = o_proj; K = 1024; N = 1024; lid = bid - 3072;
  } else if (bid < 8192) {
    in = w_fc; out = o_fc; K = 1024; N = 4096; lid = bid - 4096;
  } else {
    in = w_fc2; out = o_fc2; K = 4096; N = 1024; lid = bid - 8192;
  }
  int gx = N >> 5;
  int n0 = (lid % gx) * 32, k0 = (lid / gx) * 32;
  int tx = threadIdx.x & 31, ty = threadIdx.x >> 5;
#pragma unroll
  for (int i = 0; i < 32; i += 8)
    t[ty + i][tx] = in[(size_t)(k0 + ty + i) * N + n0 + tx];
  __syncthreads();
#pragma unroll
  for (int i = 0; i < 32; i += 8)
    out[(size_t)(n0 + ty + i) * K + k0 + tx] = f2bf(t[tx][ty + i]);
}

// ---------------- V transpose: qkv V-part -> Vt[bh][64][2048] bf16 ----------------
__global__ __launch_bounds__(256) void k_transpose_v(
    const unsigned short* __restrict__ qkv, unsigned short* __restrict__ Vt) {
  __shared__ unsigned short t[32][33];
  int tx = threadIdx.x & 31, ty = threadIdx.x >> 5;  // 32 x 8
  int t0 = blockIdx.x * 32;
  int d0 = (blockIdx.y & 1) * 32;
  int bh = blockIdx.y >> 1;
  int b = bh >> 4, h = bh & 15;
  const unsigned short* src = qkv + (size_t)b * SEQ * THREE_EMBED + 2 * EMBED + h * HDIM;
#pragma unroll
  for (int i = 0; i < 32; i += 8)
    t[ty + i][tx] = src[(size_t)(t0 + ty + i) * THREE_EMBED + d0 + tx];
  __syncthreads();
  unsigned short* dst = Vt + (size_t)bh * HDIM * SEQ;
#pragma unroll
  for (int i = 0; i < 32; i += 8)
    dst[(size_t)(d0 + ty + i) * SEQ + t0 + tx] = t[tx][ty + i];
}

// ---------------- layernorm fp32 [4096][1024] -> bf16 ----------------
__global__ __launch_bounds__(256) void k_layernorm(
    const float* __restrict__ x, const float* __restrict__ g,
    const float* __restrict__ b, unsigned short* __restrict__ out) {
  int row = blockIdx.x;
  int tid = threadIdx.x;
  const float4 xv = *(const float4*)(x + (size_t)row * EMBED + tid * 4);
  float s = xv.x + xv.y + xv.z + xv.w;
  float sq = xv.x * xv.x + xv.y * xv.y + xv.z * xv.z + xv.w * xv.w;
#pragma unroll
  for (int off = 1; off < 64; off <<= 1) {
    s += __shfl_xor(s, off);
    sq += __shfl_xor(sq, off);
  }
  __shared__ float red[8];
  int w = tid >> 6;
  if ((tid & 63) == 0) { red[w] = s; red[4 + w] = sq; }
  __syncthreads();
  s = red[0] + red[1] + red[2] + red[3];
  sq = red[4] + red[5] + red[6] + red[7];
  float mu = s * (1.0f / EMBED);
  float var = sq * (1.0f / EMBED) - mu * mu;
  float rs = rsqrtf(var + 1e-5f);
  float xs[4] = {xv.x, xv.y, xv.z, xv.w};
  unsigned short o[4];
#pragma unroll
  for (int c = 0; c < 4; c++) {
    int col = tid * 4 + c;
    o[c] = f2bf((xs[c] - mu) * rs * g[col] + b[col]);
  }
  *(ushort4*)(out + (size_t)row * EMBED + tid * 4) = *(const ushort4*)o;
}

// ======== 256x256 8-wave 4-phase GEMM v3 (m201-skeleton phases) ========
template <int EPI>
__global__ __launch_bounds__(512, 2) void k_gemm8(
    const unsigned short* __restrict__ A, const unsigned short* __restrict__ Bt,
    const float* __restrict__ bias, const float* __restrict__ resid,
    float* __restrict__ outf, unsigned short* __restrict__ outb,
    int M, int N, int K) {
  __shared__ unsigned short lA[2][16384];
  __shared__ unsigned short lB[2][16384];
  int tid = threadIdx.x;
  int nwg = gridDim.x * gridDim.y;
  int bid = blockIdx.y * gridDim.x + blockIdx.x;
  int swz = (bid & 7) * (nwg >> 3) + (bid >> 3);
  int m0 = (swz / gridDim.x) * 256, n0 = (swz % gridDim.x) * 256;
  int lane = tid & 63, w = tid >> 6;
  int lr = lane & 15, lg = lane >> 4;
  int warow = (w >> 2) * 64;  // A row base within a half
  int wbrow = (w & 3) * 32;   // B row base within a half
  int rx = lr & 7;
  int colk[2] = {(lg ^ rx) * 8, ((4 + lg) ^ rx) * 8};
  f32x4 acc[8][4] = {};
  int swzk = ((lane & 7) ^ ((lane >> 3) & 7)) * 8;  // pre-swizzled global col (shorts)
  const unsigned short* gA[2];
  const unsigned short* gB[2];
#pragma unroll
  for (int i = 0; i < 2; i++) {
    int chrow = (w * 2 + i) * 8 + (lane >> 3);
    gA[i] = A + (size_t)(m0 + chrow) * K + swzk;
    gB[i] = Bt + (size_t)(n0 + chrow) * K + swzk;
  }
  int NT = K >> 6;
  auto stageA = [&](int h, int kt, int buf) {
    size_t goff = (size_t)(h * 128) * K + (size_t)kt * 64;
    int lo = h * 8192 + w * 1024;
    gload_lds16(gA[0] + goff, &lA[buf][lo]);
    gload_lds16(gA[1] + goff, &lA[buf][lo + 512]);
  };
  auto stageB = [&](int h, int kt, int buf) {
    size_t goff = (size_t)(h * 128) * K + (size_t)kt * 64;
    int lo = h * 8192 + w * 1024;
    gload_lds16(gB[0] + goff, &lB[buf][lo]);
    gload_lds16(gB[1] + goff, &lB[buf][lo + 512]);
  };
  bf16x8 aX[4][2], aY[4][2], b0[2][2], b1[2][2];
  auto rdA = [&](int buf, int mh, bf16x8 (&dst)[4][2]) {
#pragma unroll
    for (int ii = 0; ii < 4; ii++) {
      int ra = mh * 128 + warow + ii * 16 + lr;
#pragma unroll
      for (int ks = 0; ks < 2; ks++)
        dst[ii][ks] = *(const bf16x8*)&lA[buf][ra * 64 + colk[ks]];
    }
  };
  auto rdB = [&](int buf, int nh, bf16x8 (&dst)[2][2]) {
#pragma unroll
    for (int jj = 0; jj < 2; jj++) {
      int rb = nh * 128 + wbrow + jj * 16 + lr;
#pragma unroll
      for (int ks = 0; ks < 2; ks++)
        dst[jj][ks] = *(const bf16x8*)&lB[buf][rb * 64 + colk[ks]];
    }
  };
  auto mf = [&](int mh, int nh, bf16x8 (&aa)[4][2], bf16x8 (&bb)[2][2]) {
    __builtin_amdgcn_s_setprio(1);
#pragma unroll
    for (int ii = 0; ii < 4; ii++)
#pragma unroll
      for (int jj = 0; jj < 2; jj++)
#pragma unroll
        for (int ks = 0; ks < 2; ks++)
          acc[mh * 4 + ii][nh * 2 + jj] =
              MFMA16(aa[ii][ks], bb[jj][ks], acc[mh * 4 + ii][nh * 2 + jj]);
    __builtin_amdgcn_s_setprio(0);
  };
  stageA(0, 0, 0); stageB(0, 0, 0);   // G1(0)
  stageB(1, 0, 0); stageA(1, 0, 0);   // G2(0)
  wait_vmcnt<4>();
  __builtin_amdgcn_s_barrier();
  rdA(0, 0, aX);
  for (int t = 0; t < NT - 1; t++) {
    int cur = t & 1, nxt = cur ^ 1;
    rdB(cur, 0, b0);
    stageA(0, t + 1, nxt); stageB(0, t + 1, nxt);
    wait_vmcnt<4>();
    __builtin_amdgcn_s_barrier();
    lds_fence();
    mf(0, 0, aX, b0);
    rdB(cur, 1, b1);
    rdA(cur, 1, aY);
    __builtin_amdgcn_s_barrier();
    lds_fence();
    mf(0, 1, aX, b1);
    stageB(1, t + 1, nxt); stageA(1, t + 1, nxt);
    wait_vmcnt<4>();
    __builtin_amdgcn_s_barrier();
    lds_fence();
    mf(1, 1, aY, b1);
    rdA(nxt, 0, aX);
    __builtin_amdgcn_s_barrier();
    lds_fence();
    mf(1, 0, aY, b0);
  }
  {  // tail tile NT-1: no staging; drain remaining G2(NT-2) then finish
    int cur = (NT - 1) & 1;
    rdB(cur, 0, b0);
    wait_vmcnt<0>();
    __builtin_amdgcn_s_barrier();
    lds_fence();
    mf(0, 0, aX, b0);
    rdB(cur, 1, b1);
    rdA(cur, 1, aY);
    lds_fence();
    mf(0, 1, aX, b1);
    mf(1, 1, aY, b1);
    mf(1, 0, aY, b0);
  }
#pragma unroll
  for (int i = 0; i < 8; i++) {
#pragma unroll
    for (int j = 0; j < 4; j++) {
      int col = n0 + (j >> 1) * 128 + wbrow + (j & 1) * 16 + lr;
      float bv = bias[col];
#pragma unroll
      for (int r = 0; r < 4; r++) {
        int row = m0 + (i >> 2) * 128 + warow + (i & 3) * 16 + lg * 4 + r;
        float v = acc[i][j][r] + bv;
        size_t idx = (size_t)row * N + col;
        if constexpr (EPI == 0) {
          outb[idx] = f2bf(v);
        } else if constexpr (EPI == 1) {
          outf[idx] = v + resid[idx];
        } else {
          float gv = 0.5f * v * (1.0f + erff(v * 0.70710678118654752f));
          outb[idx] = f2bf(gv);
        }
      }
    }
  }
}

// ---- narrow GEMM (BM=128, BN=64, BK=64): 3-buffer counted-vmcnt pipeline ----
template <int EPI>
__global__ __launch_bounds__(256) void k_gemmN(
    const unsigned short* __restrict__ A, const unsigned short* __restrict__ Bt,
    const float* __restrict__ bias, const float* __restrict__ resid,
    float* __restrict__ outf, unsigned short* __restrict__ outb,
    int M, int N, int K) {
  __shared__ unsigned short lA[3][128 * 64];
  __shared__ unsigned short lB[3][64 * 64];
  int tid = threadIdx.x;
  int nwg = gridDim.x * gridDim.y;
  int bid = blockIdx.y * gridDim.x + blockIdx.x;
  int swz = (bid & 7) * (nwg >> 3) + (bid >> 3);
  int m0 = (swz / gridDim.x) * 128, n0 = (swz % gridDim.x) * 64;
  int lane = tid & 63, w = tid >> 6;
  int wm = w * 32;
  int lr = lane & 15, lg = lane >> 4;
  int rx = lr & 7;
  int colk[2] = {(lg ^ rx) * 8, ((4 + lg) ^ rx) * 8};
  f32x4 acc[2][4] = {};
  int swzk = ((lane & 7) ^ ((lane >> 3) & 7)) * 8;  // pre-swizzled global col (shorts)
  const unsigned short* gsrc[6];
  int loff[6];
  bool isa[6];
#pragma unroll
  for (int c0 = 0; c0 < 6; c0++) {
    int c = w * 6 + c0;
    if (c < 16) {
      int row = c * 8 + (lane >> 3);
      gsrc[c0] = A + (size_t)(m0 + row) * K + swzk;
      loff[c0] = c * 512;
      isa[c0] = true;
    } else {
      int row = (c - 16) * 8 + (lane >> 3);
      gsrc[c0] = Bt + (size_t)(n0 + row) * K + swzk;
      loff[c0] = (c - 16) * 512;
      isa[c0] = false;
    }
  }
  auto stage = [&](int k0, int buf) {
#pragma unroll
    for (int c0 = 0; c0 < 6; c0++)
      gload_lds16(gsrc[c0] + k0, isa[c0] ? &lA[buf][loff[c0]] : &lB[buf][loff[c0]]);
  };
  auto compute = [&](int buf) {
    bf16x8 af[2][2], bf[4][2];
#pragma unroll
    for (int i = 0; i < 2; i++)
#pragma unroll
      for (int ks = 0; ks < 2; ks++)
        af[i][ks] = *(const bf16x8*)&lA[buf][(wm + i * 16 + lr) * 64 + colk[ks]];
#pragma unroll
    for (int j = 0; j < 4; j++)
#pragma unroll
      for (int ks = 0; ks < 2; ks++)
        bf[j][ks] = *(const bf16x8*)&lB[buf][(j * 16 + lr) * 64 + colk[ks]];
    __builtin_amdgcn_s_setprio(1);
#pragma unroll
    for (int i = 0; i < 2; i++)
#pragma unroll
      for (int j = 0; j < 4; j++)
#pragma unroll
        for (int ks = 0; ks < 2; ks++)
          acc[i][j] = MFMA16(af[i][ks], bf[j][ks], acc[i][j]);
    __builtin_amdgcn_s_setprio(0);
  };
  int nt = K >> 6;
  stage(0, 0);
  stage(64, 1);
  wait_vmcnt<6>();
  __builtin_amdgcn_s_barrier();
  int c0 = 0, c1 = 1, c2 = 2;
  for (int t = 0; t < nt - 2; t++) {
    stage((t + 2) * 64, c2);
    compute(c0);
    wait_vmcnt<6>();
    __builtin_amdgcn_s_barrier();
    int tmp = c0; c0 = c1; c1 = c2; c2 = tmp;
  }
  compute(c0);
  wait_vmcnt<0>();
  __builtin_amdgcn_s_barrier();
  compute(c1);
#pragma unroll
  for (int i = 0; i < 2; i++) {
#pragma unroll
    for (int j = 0; j < 4; j++) {
      int colb = n0 + j * 16 + lr;
      float bv = bias[colb];
#pragma unroll
      for (int r = 0; r < 4; r++) {
        int row = m0 + wm + i * 16 + lg * 4 + r;
        float v = acc[i][j][r] + bv;
        size_t idx = (size_t)row * N + colb;
        if constexpr (EPI == 0) {
          outb[idx] = f2bf(v);
        } else if constexpr (EPI == 1) {
          outf[idx] = v + resid[idx];
        } else {
          float gv = 0.5f * v * (1.0f + erff(v * 0.70710678118654752f));
          outb[idx] = f2bf(gv);
        }
      }
    }
  }
}

// ---------------- causal flash attention (QBLK=64) ----------------
// Q pre-scaled by 1/8*log2e at load; lP pitch 72 (144B rows = 9 bank-quads,
// odd stride -> conflict-free aligned b128 pf reads); P->bf16 via
// v_cvt_pk_bf16_f32 pairs (saves ~40 VALU ops/iter/lane vs manual RNE).
__global__ __launch_bounds__(256) void k_attention(
    const unsigned short* __restrict__ qkv, const unsigned short* __restrict__ Vt,
    unsigned short* __restrict__ out) {
  __shared__ unsigned short lK[2][64 * 64];
  __shared__ unsigned short lV[2][64 * 64];
  __shared__ unsigned short lP[4][16][72];
  int bid = blockIdx.x;
  int i = bid >> 3;
  int qt = 31 - (i >> 2);
  int bh = (bid & 7) * 4 + (i & 3);
  int b = bh >> 4, h = bh & 15;
  int tid = threadIdx.x, lane = tid & 63, w = tid >> 6;
  int lr = lane & 15, lg = lane >> 4;
  const unsigned short* base = qkv + (size_t)b * SEQ * THREE_EMBED + h * HDIM;
  const unsigned short* Kb = base + EMBED;
  const unsigned short* Vb = Vt + (size_t)bh * HDIM * SEQ;
  int q0 = qt * 64 + w * 16;
  const float SCL = 0.125f * 1.4426950408889634f;  // 1/sqrt(64) * log2(e)
  bf16x8 qf[2];
  {
    int qrow = q0 + lr;
    bf16x8 r0 = *(const bf16x8*)(base + (size_t)qrow * THREE_EMBED + lg * 8);
    bf16x8 r1 = *(const bf16x8*)(base + (size_t)qrow * THREE_EMBED + 32 + lg * 8);
#pragma unroll
    for (int j = 0; j < 8; j++) {
      qf[0][j] = (short)f2bf(bf2f((unsigned short)r0[j]) * SCL);
      qf[1][j] = (short)f2bf(bf2f((unsigned short)r1[j]) * SCL);
    }
  }
  bf16x8 ones;
  {
    short o1 = 0x3F80;
#pragma unroll
    for (int j = 0; j < 8; j++) ones[j] = o1;
  }
  f32x4 o[4] = {};
  f32x4 osum = {};
  float m_[4] = {-INFINITY, -INFINITY, -INFINITY, -INFINITY};
  int srow = lane >> 3;
  int scol = ((lane & 7) ^ (lane >> 3)) * 8;
  int nkv = qt + 1;
  auto stage = [&](int kt, int cur) {
#pragma unroll
    for (int c = 0; c < 2; c++) {
      int chunk = w * 2 + c;
      int row = chunk * 8 + srow;
      gload_lds16(Kb + (size_t)(kt * 64 + row) * THREE_EMBED + scol, &lK[cur][chunk * 512]);
      gload_lds16(Vb + (size_t)row * SEQ + kt * 64 + scol, &lV[cur][chunk * 512]);
    }
  };
  stage(0, 0);
  wait_vm0_barrier();
  int cur = 0;
  for (int kt = 0; kt < nkv; kt++) {
    if (kt + 1 < nkv) stage(kt + 1, cur ^ 1);
    __builtin_amdgcn_s_setprio(1);
    f32x4 s[4];
#pragma unroll
    for (int ct = 0; ct < 4; ct++) {
      int krow = ct * 16 + lr;
      int sw = (krow & 7) << 3;
      bf16x8 k0 = *(const bf16x8*)&lK[cur][krow * 64 + ((lg * 8) ^ sw)];
      bf16x8 k1 = *(const bf16x8*)&lK[cur][krow * 64 + ((32 + lg * 8) ^ sw)];
      f32x4 z = {};
      z = MFMA16(qf[0], k0, z);
      s[ct] = MFMA16(qf[1], k1, z);
    }
    __builtin_amdgcn_s_setprio(0);
    bool maskt = (kt * 64 + 63 > q0);
    float pm[4] = {-INFINITY, -INFINITY, -INFINITY, -INFINITY};
#pragma unroll
    for (int ct = 0; ct < 4; ct++) {
#pragma unroll
      for (int r = 0; r < 4; r++) {
        float sv = s[ct][r];  // SCL pre-folded into Q
        if (maskt) {
          int kg = kt * 64 + ct * 16 + lr;
          int qg = q0 + lg * 4 + r;
          if (kg > qg) sv = -INFINITY;
        }
        s[ct][r] = sv;
        pm[r] = fmaxf(pm[r], sv);
      }
    }
    float dm = fmaxf(fmaxf(pm[0] - m_[0], pm[1] - m_[1]),
                     fmaxf(pm[2] - m_[2], pm[3] - m_[3]));
    if (!__all(dm <= 8.0f)) {
#pragma unroll
      for (int r = 0; r < 4; r++) {
        float mx = pm[r];
        mx = fmaxf(mx, __shfl_xor(mx, 1));
        mx = fmaxf(mx, __shfl_xor(mx, 2));
        mx = fmaxf(mx, __shfl_xor(mx, 4));
        mx = fmaxf(mx, __shfl_xor(mx, 8));
        float mn = fmaxf(m_[r], mx);
        float al = exp2f(m_[r] - mn);
        m_[r] = mn;
        osum[r] *= al;
#pragma unroll
        for (int dt = 0; dt < 4; dt++) o[dt][r] *= al;
      }
    }
    // P = exp2(S - m) -> bf16 via cvt_pk pairs -> LDS
#pragma unroll
    for (int ct = 0; ct < 4; ct++) {
#pragma unroll
      for (int rp = 0; rp < 2; rp++) {
        float p0 = exp2f(s[ct][2 * rp] - m_[2 * rp]);
        float p1 = exp2f(s[ct][2 * rp + 1] - m_[2 * rp + 1]);
        unsigned int pk;
        asm("v_cvt_pk_bf16_f32 %0, %1, %2" : "=v"(pk) : "v"(p0), "v"(p1));
        lP[w][lg * 4 + 2 * rp][ct * 16 + lr] = (unsigned short)pk;
        lP[w][lg * 4 + 2 * rp + 1][ct * 16 + lr] = (unsigned short)(pk >> 16);
      }
    }
    __builtin_amdgcn_s_setprio(1);
#pragma unroll
    for (int ks = 0; ks < 2; ks++) {
      bf16x8 pf = *(const bf16x8*)&lP[w][lr][ks * 32 + lg * 8];
      osum = MFMA16(pf, ones, osum);
#pragma unroll
      for (int dt = 0; dt < 4; dt++) {
        int vrow = dt * 16 + lr;
        int sw = (vrow & 7) << 3;
        bf16x8 vf = *(const bf16x8*)&lV[cur][vrow * 64 + ((ks * 32 + lg * 8) ^ sw)];
        o[dt] = MFMA16(pf, vf, o[dt]);
      }
    }
    __builtin_amdgcn_s_setprio(0);
    wait_vm0_barrier();
    cur ^= 1;
  }
#pragma unroll
  for (int dt = 0; dt < 4; dt++)
#pragma unroll
    for (int r = 0; r < 4; r++) {
      int row = q0 + lg * 4 + r;
      float val = o[dt][r] / osum[r];
      out[(size_t)(b * SEQ + row) * EMBED + h * HDIM + dt * 16 + lr] = f2bf(val);
    }
}

extern "C" void kernel_launch(void* const* d_in, const int* in_sizes, int n_in,
                              void* d_out, int out_size, void* d_ws, size_t ws_size,
                              hipStream_t stream) {
  const float* x      = (const float*)d_in[0];
  const float* ln1_g  = (const float*)d_in[1];
  const float* ln1_b  = (const float*)d_in[2];
  const float* w_attn = (const float*)d_in[3];
  const float* b_attn = (const float*)d_in[4];
  const float* w_proj = (const float*)d_in[5];
  const float* b_proj = (const float*)d_in[6];
  const float* ln2_g  = (const float*)d_in[7];
  const float* ln2_b  = (const float*)d_in[8];
  const float* w_fc   = (const float*)d_in[9];
  const float* b_fc   = (const float*)d_in[10];
  const float* w_fc2  = (const float*)d_in[11];
  const float* b_fc2  = (const float*)d_in[12];
  float* outp = (float*)d_out;

  char* ws = (char*)d_ws;
  unsigned short* wT_attn = (unsigned short*)(ws);             // [3072][1024] bf16, 6 MB
  unsigned short* wT_proj = (unsigned short*)(ws + 6291456);   // [1024][1024] bf16, 2 MB
  unsigned short* wT_fc   = (unsigned short*)(ws + 8388608);   // [4096][1024] bf16, 8 MB
  unsigned short* wT_fc2  = (unsigned short*)(ws + 16777216);  // [1024][4096] bf16, 8 MB
  unsigned short* buf1    = (unsigned short*)(ws + 25165824);  // 8 MB: xln -> attnout -> x2ln
  float*          x1      = (float*)(ws + 33554432);           // 16 MB fp32 (written after attention)
  unsigned short* Vt      = (unsigned short*)(ws + 33554432);  // 8 MB bf16, dead once attention done
  unsigned short* qkv_h   = (unsigned short*)(ws + 50331648);  // 24 MB qkv -> 32 MB h (48..80 MB)

  dim3 blk(256);
  // all 4 weight transposes in one launch (12288 blocks)
  k_transpose_all<<<dim3(12288), blk, 0, stream>>>(
      w_attn, w_proj, w_fc, w_fc2, wT_attn, wT_proj, wT_fc, wT_fc2);
  // LN1: x -> xln (buf1)
  k_layernorm<<<dim3(MTOT), blk, 0, stream>>>(x, ln1_g, ln1_b, buf1);
  // QKV: 256^2 v3, 12x16 = 192 blocks
  k_gemm8<0><<<dim3(THREE_EMBED / 256, MTOT / 256), dim3(512), 0, stream>>>(
      buf1, wT_attn, b_attn, nullptr, nullptr, qkv_h, MTOT, THREE_EMBED, EMBED);
  // V transpose for attention
  k_transpose_v<<<dim3(SEQ / 32, 2 * BATCH * HEADS), blk, 0, stream>>>(qkv_h, Vt);
  // attention -> attnout (buf1): 32 q-tiles x 32 bh = 1024 blocks
  k_attention<<<dim3(1024), blk, 0, stream>>>(qkv_h, Vt, buf1);
  // proj + residual: narrow BK=64, 16x32 = 512 blocks (overwrites Vt — dead)
  k_gemmN<1><<<dim3(EMBED / 64, MTOT / 128), blk, 0, stream>>>(
      buf1, wT_proj, b_proj, x, x1, nullptr, MTOT, EMBED, EMBED);
  // LN2: x1 -> x2ln (buf1)
  k_layernorm<<<dim3(MTOT), blk, 0, stream>>>(x1, ln2_g, ln2_b, buf1);
  // FC1 + GELU: 256^2 v3, 16x16 = 256 blocks
  k_gemm8<2><<<dim3(4 * EMBED / 256, MTOT / 256), dim3(512), 0, stream>>>(
      buf1, wT_fc, b_fc, nullptr, nullptr, qkv_h, MTOT, 4 * EMBED, EMBED);
  // FC2 + residual -> out: narrow BK=64, 512 blocks
  k_gemmN<1><<<dim3(EMBED / 64, MTOT / 128), blk, 0, stream>>>(
      qkv_h, wT_fc2, b_fc2, x1, outp, nullptr, MTOT, EMBED, 4 * EMBED);
}